// Round 14
// baseline (1065.110 us; speedup 1.0000x reference)
//
#include <hip/hip_runtime.h>
#include <hip/hip_bf16.h>
#include <float.h>
#include <math.h>

#define K_DIM 768
#define V_DIM 50257
#define PADV  50304              // 393*128 padded vocab
#define M_TOT 4096
#define EMB_N 3145728            // 2*2048*768
#define TAB_N 38597376           // 50257*768
#define NT128 393                // N tiles of 128
#define GSPLIT 32                // N splits for MFMA kernel
#define NCAND 64                 // GSPLIT * top2
#define NSPLIT 16                // fallback fp32 kernel splits
#define NTILES ((V_DIM + 127) / 128)
#define NOISE_BLK (EMB_N / 256)                // 12288
#define BSPLIT_BLK ((PADV * K_DIM / 4) / 256)  // 37728

typedef __attribute__((ext_vector_type(8))) short short8;
typedef __attribute__((ext_vector_type(4))) float f32x4;
typedef unsigned long long u64;

// ---------------- JAX threefry2x32 (key = (0, 42)), 20 rounds ----------------
__device__ __forceinline__ unsigned rotl32(unsigned v, int d) {
  return (v << d) | (v >> (32 - d));
}
__device__ __forceinline__ void threefry2x32_042(unsigned& x0, unsigned& x1) {
  const unsigned ks0 = 0u, ks1 = 42u;
  const unsigned ks2 = ks0 ^ ks1 ^ 0x1BD11BDAu;
  x0 += ks0; x1 += ks1;
#define TF_R(r) { x0 += x1; x1 = rotl32(x1, (r)); x1 ^= x0; }
  TF_R(13) TF_R(15) TF_R(26) TF_R(6)
  x0 += ks1; x1 += ks2 + 1u;
  TF_R(17) TF_R(29) TF_R(16) TF_R(24)
  x0 += ks2; x1 += ks0 + 2u;
  TF_R(13) TF_R(15) TF_R(26) TF_R(6)
  x0 += ks0; x1 += ks1 + 3u;
  TF_R(17) TF_R(29) TF_R(16) TF_R(24)
  x0 += ks1; x1 += ks2 + 4u;
  TF_R(13) TF_R(15) TF_R(26) TF_R(6)
  x0 += ks2; x1 += ks0 + 5u;
#undef TF_R
}

// bits -> uniform(-1+2^-24, 1) -> laplace -> /5  (exact JAX op sequence)
__device__ __forceinline__ float bits_to_noise(unsigned bits) {
  unsigned fb = (bits >> 9) | 0x3F800000u;
  float f = __uint_as_float(fb) - 1.0f;
  const float minv = -0.99999994039535522461f;
  float u = __fadd_rn(__fmul_rn(f, 2.0f), minv);
  u = fmaxf(minv, u);
  float s = (u > 0.0f) ? 1.0f : ((u < 0.0f) ? -1.0f : 0.0f);
  float l = s * log1pf(-fabsf(u));
  return __fdiv_rn(l, 5.0f);
}

__device__ __forceinline__ float bf2f(unsigned short b) {
  return __uint_as_float(((unsigned)b) << 16);
}
__device__ __forceinline__ unsigned short f2bf(float x) {
  __hip_bfloat16 h = __float2bfloat16(x);   // RNE
  return *(unsigned short*)&h;
}

// monotone u32 key of float (order-preserving)
__device__ __forceinline__ unsigned fkey(float v) {
  unsigned b = __float_as_uint(v);
  return b ^ (((unsigned)((int)b >> 31)) | 0x80000000u);
}
// u64 (value,index) pack for exact paths
__device__ __forceinline__ u64 pack_maxidx(float v, unsigned idx) {
  return ((u64)fkey(v) << 32) | (u64)(0xFFFFFFFFu - idx);
}
__device__ __forceinline__ unsigned umax32(unsigned a, unsigned b) { return a > b ? a : b; }
__device__ __forceinline__ unsigned umin32(unsigned a, unsigned b) { return a < b ? a : b; }

__device__ __forceinline__ void gload16(const void* g, void* l) {
  __builtin_amdgcn_global_load_lds(
      (const __attribute__((address_space(1))) unsigned*)g,
      (__attribute__((address_space(3))) unsigned*)l, 16, 0, 0);
}

// ============================ FAST PATH ====================================

// fused prep: noisy(f32)->d_out + Ah bf16; table -> Bh bf16 (padded zeroed)
__global__ void prep_kernel(const float* __restrict__ in,
                            const float* __restrict__ tab,
                            float* __restrict__ noisy,
                            unsigned short* __restrict__ Ah,
                            unsigned short* __restrict__ Bh) {
  if (blockIdx.x < NOISE_BLK) {
    const unsigned i = blockIdx.x * 256 + threadIdx.x;
    unsigned x0 = 0u, x1 = i;
    threefry2x32_042(x0, x1);
    float v = in[i] + bits_to_noise(x0 ^ x1);
    noisy[i] = v;
    Ah[i] = f2bf(v);
  } else {
    const size_t i = ((size_t)(blockIdx.x - NOISE_BLK) * 256 + threadIdx.x) * 4;
    ushort4 h;
    if (i < (size_t)TAB_N) {
      float4 v = *(const float4*)(tab + i);
      h.x = f2bf(v.x); h.y = f2bf(v.y); h.z = f2bf(v.z); h.w = f2bf(v.w);
    } else {
      h = make_ushort4(0, 0, 0, 0);
    }
    *(ushort4*)(Bh + i) = h;
  }
}

// bf16 MFMA GEMM (BK=64, round-10 verified structure) + XCD-aware remap.
// 1D grid of 1024 blocks; idp = (id&7)*128 + (id>>3) is bijective, giving
// each XCD 4 consecutive splits (B working set 784KB -> L2-resident).
// LDS: 128 rows x 128B; 16B-slot p swizzled p = q ^ (row&7); staged linearly
// via global_load_lds with pre-swizzled global source (both-sides rule).
// Per-tile top-2 fold with u32 packed keys (verified round-10).
__global__ __launch_bounds__(256) void mfma_cand_kernel(
    const unsigned short* __restrict__ Ah,
    const unsigned short* __restrict__ Bh,
    unsigned* __restrict__ cand) {
  __shared__ alignas(16) char ldsA[16384];
  __shared__ alignas(16) char ldsB[16384];
  __shared__ unsigned topscr[128][2][2];

  const int tid = threadIdx.x, lane = tid & 63, w = tid >> 6;
  const int fr = lane & 15, g = lane >> 4;
  const int wr = (w >> 1) * 64, wc = (w & 1) * 64;

  // XCD-aware decode: XCD k gets splits [4k, 4k+4) across all 32 bm
  const int idp = (blockIdx.x & 7) * 128 + (blockIdx.x >> 3);
  const int bm = idp & 31, split = idp >> 5;

  // staging descriptors: 4 issues per operand per K-step
  int srow[4], scol[4], soff[4];
#pragma unroll
  for (int i = 0; i < 4; ++i) {
    int s = i * 256 + w * 64 + lane;        // LDS 16B-slot index 0..1023
    int row = s >> 3, p = s & 7;
    srow[i] = row;
    scol[i] = (p ^ (row & 7)) * 8;          // source element offset (bf16)
    soff[i] = i * 4096 + w * 1024;          // wave-uniform LDS byte base
  }

  unsigned run1 = 0u, run2 = 0u;   // running per-row top-2 (tid<128 only)

  int tidx = 0;   // tile counter within split (0..12)
  for (int t = split; t < NT128; t += GSPLIT, ++tidx) {
    f32x4 acc[4][4];
#pragma unroll
    for (int m = 0; m < 4; ++m)
#pragma unroll
      for (int n = 0; n < 4; ++n) acc[m][n] = (f32x4){0.f, 0.f, 0.f, 0.f};

    const size_t abase = (size_t)bm * 128 * K_DIM;
    const size_t bbase = (size_t)t * 128 * K_DIM;

    for (int ks = 0; ks < K_DIM / 64; ++ks) {
      const int k0 = ks * 64;
      __syncthreads();
#pragma unroll
      for (int i = 0; i < 4; ++i) {
        gload16(Ah + abase + (size_t)srow[i] * K_DIM + k0 + scol[i], ldsA + soff[i]);
        gload16(Bh + bbase + (size_t)srow[i] * K_DIM + k0 + scol[i], ldsB + soff[i]);
      }
      __syncthreads();

      short8 af[4][2], bf[4][2];
#pragma unroll
      for (int m = 0; m < 4; ++m) {
        const int row = wr + m * 16 + fr;
#pragma unroll
        for (int k2 = 0; k2 < 2; ++k2) {
          const int p = (k2 * 4 + g) ^ (row & 7);
          af[m][k2] = *(const short8*)(ldsA + row * 128 + p * 16);
        }
      }
#pragma unroll
      for (int n = 0; n < 4; ++n) {
        const int row = wc + n * 16 + fr;
#pragma unroll
        for (int k2 = 0; k2 < 2; ++k2) {
          const int p = (k2 * 4 + g) ^ (row & 7);
          bf[n][k2] = *(const short8*)(ldsB + row * 128 + p * 16);
        }
      }
#pragma unroll
      for (int m = 0; m < 4; ++m)
#pragma unroll
        for (int n = 0; n < 4; ++n) {
          acc[m][n] = __builtin_amdgcn_mfma_f32_16x16x32_bf16(af[m][0], bf[n][0], acc[m][n], 0, 0, 0);
          acc[m][n] = __builtin_amdgcn_mfma_f32_16x16x32_bf16(af[m][1], bf[n][1], acc[m][n], 0, 0, 0);
        }
    }

    // per-tile top-2 per row, u32 keys; C/D: col=lane&15, row=g*4+j
    unsigned lowf[4];
#pragma unroll
    for (int n = 0; n < 4; ++n)
      lowf[n] = 2047u - (unsigned)(tidx * 128 + wc + n * 16 + fr);

#pragma unroll
    for (int m = 0; m < 4; ++m)
#pragma unroll
      for (int j = 0; j < 4; ++j) {
        unsigned p0 = (fkey(acc[m][0][j]) & 0xFFFFF800u) | lowf[0];
        unsigned p1 = (fkey(acc[m][1][j]) & 0xFFFFF800u) | lowf[1];
        unsigned p2 = (fkey(acc[m][2][j]) & 0xFFFFF800u) | lowf[2];
        unsigned p3 = (fkey(acc[m][3][j]) & 0xFFFFF800u) | lowf[3];
        unsigned a1 = umax32(p0, p1), a2 = umin32(p0, p1);
        unsigned b1 = umax32(p2, p3), b2 = umin32(p2, p3);
        unsigned t1 = umax32(a1, b1);
        unsigned t2 = umax32(umin32(a1, b1), umax32(a2, b2));
#pragma unroll
        for (int msk = 1; msk < 16; msk <<= 1) {
          unsigned o1 = (unsigned)__shfl_xor((int)t1, msk, 64);
          unsigned o2 = (unsigned)__shfl_xor((int)t2, msk, 64);
          if (o1 > t1) { t2 = umax32(t1, o2); t1 = o1; }
          else t2 = umax32(t2, o1);
        }
        if (fr == 0) {
          int rl = wr + m * 16 + g * 4 + j;
          topscr[rl][w & 1][0] = t1;
          topscr[rl][w & 1][1] = t2;
        }
      }
    __syncthreads();
    if (tid < 128) {
      unsigned a1 = topscr[tid][0][0], a2 = topscr[tid][0][1];
      unsigned b1 = topscr[tid][1][0], b2 = topscr[tid][1][1];
      unsigned m1, m2;
      if (a1 > b1) { m1 = a1; m2 = umax32(a2, b1); }
      else         { m1 = b1; m2 = umax32(b2, a1); }
      if (m1 > run1) { run2 = umax32(run1, m2); run1 = m1; }
      else run2 = umax32(run2, m1);
    }
  }

  if (tid < 128) {
    unsigned l1 = 2047u - (run1 & 0x7FFu);
    unsigned l2 = 2047u - (run2 & 0x7FFu);
    unsigned c1 = (unsigned)((split + (l1 >> 7) * GSPLIT) * 128) + (l1 & 127u);
    unsigned c2 = (unsigned)((split + (l2 >> 7) * GSPLIT) * 128) + (l2 & 127u);
    if (c1 >= V_DIM) c1 = 0;
    if (c2 >= V_DIM) c2 = 0;
    int grow = bm * 128 + tid;
    cand[(grow * GSPLIT + split) * 2 + 0] = c1;
    cand[(grow * GSPLIT + split) * 2 + 1] = c2;
  }
}

// fp32 rescore of 64 candidates/row, coalesced (verified rounds 11-13)
__global__ __launch_bounds__(256) void rescore_kernel(
    const float* __restrict__ noisy, const float* __restrict__ table,
    const unsigned* __restrict__ cand, u64* __restrict__ merged) {
  __shared__ u64 wbest[4];
  const int row = blockIdx.x;
  const int tid = threadIdx.x, lane = tid & 63, wv = tid >> 6;
  const float* a = noisy + (size_t)row * K_DIM + lane * 12;
  float4 a0 = *(const float4*)(a);
  float4 a1 = *(const float4*)(a + 4);
  float4 a2 = *(const float4*)(a + 8);

  u64 best = 0;
  for (int c = wv; c < NCAND; c += 4) {
    const unsigned ci = cand[row * NCAND + c];
    const float* b = table + (size_t)ci * K_DIM + lane * 12;
    float4 b0 = *(const float4*)(b);
    float4 b1 = *(const float4*)(b + 4);
    float4 b2 = *(const float4*)(b + 8);
    float s = 0.f;
    s = fmaf(a0.x, b0.x, s); s = fmaf(a0.y, b0.y, s);
    s = fmaf(a0.z, b0.z, s); s = fmaf(a0.w, b0.w, s);
    s = fmaf(a1.x, b1.x, s); s = fmaf(a1.y, b1.y, s);
    s = fmaf(a1.z, b1.z, s); s = fmaf(a1.w, b1.w, s);
    s = fmaf(a2.x, b2.x, s); s = fmaf(a2.y, b2.y, s);
    s = fmaf(a2.z, b2.z, s); s = fmaf(a2.w, b2.w, s);
#pragma unroll
    for (int m = 1; m < 64; m <<= 1) s += __shfl_xor(s, m, 64);
    u64 p = pack_maxidx(s, ci);
    if (p > best) best = p;
  }
  if (lane == 0) wbest[wv] = best;
  __syncthreads();
  if (tid == 0) {
    u64 b0_ = wbest[0], b1_ = wbest[1], b2_ = wbest[2], b3_ = wbest[3];
    u64 m01 = b0_ > b1_ ? b0_ : b1_;
    u64 m23 = b2_ > b3_ ? b2_ : b3_;
    merged[row] = m01 > m23 ? m01 : m23;
  }
}

// ============================ FALLBACK (verified round-6) ===================

__global__ void noise_add_kernel(const float* __restrict__ in,
                                 float* __restrict__ noisy,
                                 u64* __restrict__ merged) {
  const unsigned i = blockIdx.x * blockDim.x + threadIdx.x;
  if (i >= EMB_N) return;
  if (i < M_TOT) merged[i] = 0ull;
  unsigned x0 = 0u, x1 = i;
  threefry2x32_042(x0, x1);
  noisy[i] = in[i] + bits_to_noise(x0 ^ x1);
}

__global__ __launch_bounds__(256) void gemm_argmax_kernel(
    const float* __restrict__ noisy, const float* __restrict__ table,
    u64* __restrict__ merged) {
  __shared__ float As[16][132];
  __shared__ float Bs[16][132];
  __shared__ float redm[128][16];
  __shared__ int   redi[128][16];

  const int tid = threadIdx.x;
  const int lane = tid & 63;
  const int w = tid >> 6;
  const int tx = lane & 7, ty = lane >> 3;
  const int col0 = (w & 1) * 64 + tx * 8;
  const int row0 = (w >> 1) * 64 + ty * 8;
  const int bm = blockIdx.x;
  const int split = blockIdx.y;
  const float* Abase = noisy + (size_t)bm * 128 * K_DIM;

  float rmax[8]; int ridx[8];
#pragma unroll
  for (int r = 0; r < 8; ++r) { rmax[r] = -INFINITY; ridx[r] = 0x7FFFFFFF; }

  for (int t = split; t < NTILES; t += NSPLIT) {
    const int nbase = t * 128;
    float acc[8][8];
#pragma unroll
    for (int r = 0; r < 8; ++r)
#pragma unroll
      for (int c = 0; c < 8; ++c) acc[r][c] = 0.0f;

    for (int k0 = 0; k0 < K_DIM; k0 += 16) {
      __syncthreads();
#pragma unroll
      for (int l = 0; l < 2; ++l) {
        const int e = tid + l * 256;
        const int ml = e >> 2, kk = (e & 3) << 2;
        float4 av = *(const float4*)(Abase + (size_t)ml * K_DIM + k0 + kk);
        As[kk + 0][ml] = av.x; As[kk + 1][ml] = av.y;
        As[kk + 2][ml] = av.z; As[kk + 3][ml] = av.w;
        const int n = nbase + ml;
        float4 bv = make_float4(0.f, 0.f, 0.f, 0.f);
        if (n < V_DIM)
          bv = *(const float4*)(table + (size_t)n * K_DIM + k0 + kk);
        Bs[kk + 0][ml] = bv.x; Bs[kk + 1][ml] = bv.y;
        Bs[kk + 2][ml] = bv.z; Bs[kk + 3][ml] = bv.w;
      }
      __syncthreads();
#pragma unroll
      for (int k = 0; k < 16; ++k) {
        float4 a0 = *(const float4*)&As[k][row0];
        float4 a1 = *(const float4*)&As[k][row0 + 4];
        float4 b0 = *(const float4*)&Bs[k][col0];
        float4 b1 = *(const float4*)&Bs[k][col0 + 4];
        float a[8] = {a0.x, a0.y, a0.z, a0.w, a1.x, a1.y, a1.z, a1.w};
        float b[8] = {b0.x, b0.y, b0.z, b0.w, b1.x, b1.y, b1.z, b1.w};
#pragma unroll
        for (int r = 0; r < 8; ++r)
#pragma unroll
          for (int c = 0; c < 8; ++c)
            acc[r][c] = fmaf(a[r], b[c], acc[r][c]);
      }
    }
#pragma unroll
    for (int r = 0; r < 8; ++r)
#pragma unroll
      for (int c = 0; c < 8; ++c) {
        const int n = nbase + col0 + c;
        if (n < V_DIM && acc[r][c] > rmax[r]) { rmax[r] = acc[r][c]; ridx[r] = n; }
      }
  }

  __syncthreads();
#pragma unroll
  for (int r = 0; r < 8; ++r) {
    redm[row0 + r][(w & 1) * 8 + tx] = rmax[r];
    redi[row0 + r][(w & 1) * 8 + tx] = ridx[r];
  }
  __syncthreads();
  if (tid < 128) {
    float best = -INFINITY; int bi = 0x7FFFFFFF;
#pragma unroll
    for (int j = 0; j < 16; ++j) {
      float v = redm[tid][j]; int id = redi[tid][j];
      if (v > best || (v == best && id < bi)) { best = v; bi = id; }
    }
    atomicMax(&merged[bm * 128 + tid], pack_maxidx(best, (unsigned)bi));
  }
}

// ---------------- shared: unpack index + gather table row -------------------
__global__ void gather_kernel(const u64* __restrict__ merged,
                              const float* __restrict__ table,
                              float* __restrict__ out) {
  const int row = blockIdx.x;
  const int tid = threadIdx.x;
  const unsigned bi = 0xFFFFFFFFu - (unsigned)(merged[row] & 0xFFFFFFFFull);
  if (tid < 192) {
    float4 val = *(const float4*)(table + (size_t)bi * K_DIM + tid * 4);
    *(float4*)(out + (size_t)row * K_DIM + tid * 4) = val;
  }
}

// ---------------- launch ----------------
extern "C" void kernel_launch(void* const* d_in, const int* in_sizes, int n_in,
                              void* d_out, int out_size, void* d_ws, size_t ws_size,
                              hipStream_t stream) {
  const float* inputs = (const float*)d_in[0];
  const float* table  = (const float*)d_in[1];
  if (n_in >= 2 && (in_sizes[0] == TAB_N || in_sizes[1] == EMB_N)) {
    table  = (const float*)d_in[0];
    inputs = (const float*)d_in[1];
  }
  float* out = (float*)d_out;
  float* noisy = out;   // overwritten by gather at the end

  // fast-path ws layout (bytes)
  const size_t oAh = 0;
  const size_t oBh = oAh + (size_t)EMB_N * 2;            //  6,291,456
  const size_t oCand = oBh + (size_t)PADV * K_DIM * 2;   // 83,558,400
  const size_t oMerged = oCand + (size_t)M_TOT * NCAND * 4;
  const size_t REQ = oMerged + (size_t)M_TOT * 8;        // ~84.6 MB

  if (ws_size >= REQ) {
    unsigned short* Ah = (unsigned short*)((char*)d_ws + oAh);
    unsigned short* Bh = (unsigned short*)((char*)d_ws + oBh);
    unsigned* cand = (unsigned*)((char*)d_ws + oCand);
    u64* merged = (u64*)((char*)d_ws + oMerged);

    prep_kernel<<<NOISE_BLK + BSPLIT_BLK, 256, 0, stream>>>(inputs, table, noisy, Ah, Bh);
    mfma_cand_kernel<<<1024, 256, 0, stream>>>(Ah, Bh, cand);
    rescore_kernel<<<M_TOT, 256, 0, stream>>>(noisy, table, cand, merged);
    gather_kernel<<<M_TOT, 256, 0, stream>>>(merged, table, out);
  } else {
    u64* merged = (u64*)d_ws;
    noise_add_kernel<<<EMB_N / 256, 256, 0, stream>>>(inputs, noisy, merged);
    dim3 g2(M_TOT / 128, NSPLIT);
    gemm_argmax_kernel<<<g2, 256, 0, stream>>>(noisy, table, merged);
    gather_kernel<<<M_TOT, 256, 0, stream>>>(merged, table, out);
  }
}

// Round 15
// 601.748 us; speedup vs baseline: 1.7700x; 1.7700x over previous
//
#include <hip/hip_runtime.h>
#include <hip/hip_bf16.h>
#include <float.h>
#include <math.h>

#define K_DIM 768
#define V_DIM 50257
#define PADV  50304              // 393*128 padded vocab
#define M_TOT 4096
#define EMB_N 3145728            // 2*2048*768
#define TAB_N 38597376           // 50257*768
#define NT128 393                // N tiles of 128
#define GSPLIT 32                // N splits for MFMA kernel
#define NCAND 64                 // GSPLIT * top2
#define NSPLIT 16                // fallback fp32 kernel splits
#define NTILES ((V_DIM + 127) / 128)
#define NOISE_BLK (EMB_N / 256)                // 12288
#define BSPLIT_BLK ((PADV * K_DIM / 4) / 256)  // 37728

typedef __attribute__((ext_vector_type(8))) short short8;
typedef __attribute__((ext_vector_type(4))) float f32x4;
typedef unsigned long long u64;

// ---------------- JAX threefry2x32 (key = (0, 42)), 20 rounds ----------------
__device__ __forceinline__ unsigned rotl32(unsigned v, int d) {
  return (v << d) | (v >> (32 - d));
}
__device__ __forceinline__ void threefry2x32_042(unsigned& x0, unsigned& x1) {
  const unsigned ks0 = 0u, ks1 = 42u;
  const unsigned ks2 = ks0 ^ ks1 ^ 0x1BD11BDAu;
  x0 += ks0; x1 += ks1;
#define TF_R(r) { x0 += x1; x1 = rotl32(x1, (r)); x1 ^= x0; }
  TF_R(13) TF_R(15) TF_R(26) TF_R(6)
  x0 += ks1; x1 += ks2 + 1u;
  TF_R(17) TF_R(29) TF_R(16) TF_R(24)
  x0 += ks2; x1 += ks0 + 2u;
  TF_R(13) TF_R(15) TF_R(26) TF_R(6)
  x0 += ks0; x1 += ks1 + 3u;
  TF_R(17) TF_R(29) TF_R(16) TF_R(24)
  x0 += ks1; x1 += ks2 + 4u;
  TF_R(13) TF_R(15) TF_R(26) TF_R(6)
  x0 += ks2; x1 += ks0 + 5u;
#undef TF_R
}

// bits -> uniform(-1+2^-24, 1) -> laplace -> /5  (exact JAX op sequence)
__device__ __forceinline__ float bits_to_noise(unsigned bits) {
  unsigned fb = (bits >> 9) | 0x3F800000u;
  float f = __uint_as_float(fb) - 1.0f;
  const float minv = -0.99999994039535522461f;
  float u = __fadd_rn(__fmul_rn(f, 2.0f), minv);
  u = fmaxf(minv, u);
  float s = (u > 0.0f) ? 1.0f : ((u < 0.0f) ? -1.0f : 0.0f);
  float l = s * log1pf(-fabsf(u));
  return __fdiv_rn(l, 5.0f);
}

__device__ __forceinline__ float bf2f(unsigned short b) {
  return __uint_as_float(((unsigned)b) << 16);
}
__device__ __forceinline__ unsigned short f2bf(float x) {
  __hip_bfloat16 h = __float2bfloat16(x);   // RNE
  return *(unsigned short*)&h;
}

// monotone u32 key of float (order-preserving)
__device__ __forceinline__ unsigned fkey(float v) {
  unsigned b = __float_as_uint(v);
  return b ^ (((unsigned)((int)b >> 31)) | 0x80000000u);
}
// u64 (value,index) pack for exact paths
__device__ __forceinline__ u64 pack_maxidx(float v, unsigned idx) {
  return ((u64)fkey(v) << 32) | (u64)(0xFFFFFFFFu - idx);
}
__device__ __forceinline__ unsigned umax32(unsigned a, unsigned b) { return a > b ? a : b; }
__device__ __forceinline__ unsigned umin32(unsigned a, unsigned b) { return a < b ? a : b; }

__device__ __forceinline__ void gload16(const void* g, void* l) {
  __builtin_amdgcn_global_load_lds(
      (const __attribute__((address_space(1))) unsigned*)g,
      (__attribute__((address_space(3))) unsigned*)l, 16, 0, 0);
}

// ============================ FAST PATH ====================================

// fused prep: noisy(f32)->d_out + Ah bf16; table -> Bh bf16 (padded zeroed)
__global__ void prep_kernel(const float* __restrict__ in,
                            const float* __restrict__ tab,
                            float* __restrict__ noisy,
                            unsigned short* __restrict__ Ah,
                            unsigned short* __restrict__ Bh) {
  if (blockIdx.x < NOISE_BLK) {
    const unsigned i = blockIdx.x * 256 + threadIdx.x;
    unsigned x0 = 0u, x1 = i;
    threefry2x32_042(x0, x1);
    float v = in[i] + bits_to_noise(x0 ^ x1);
    noisy[i] = v;
    Ah[i] = f2bf(v);
  } else {
    const size_t i = ((size_t)(blockIdx.x - NOISE_BLK) * 256 + threadIdx.x) * 4;
    ushort4 h;
    if (i < (size_t)TAB_N) {
      float4 v = *(const float4*)(tab + i);
      h.x = f2bf(v.x); h.y = f2bf(v.y); h.z = f2bf(v.z); h.w = f2bf(v.w);
    } else {
      h = make_ushort4(0, 0, 0, 0);
    }
    *(ushort4*)(Bh + i) = h;
  }
}

// bf16 MFMA GEMM (BK=64), round-10 verified structure, 2D grid (bm, split).
// Default dispatch gives XCD k the bm set {k, k+8, k+16, k+24} -> A tiles
// L2-resident (784KB); B panels shared via timing. (r14's remap inverted
// this and thrashed A -- do not "fix" the mapping.)
// LDS: 128 rows x 128B; 16B-slot p swizzled p = q ^ (row&7); staged linearly
// via global_load_lds with pre-swizzled global source (both-sides rule).
// Per-tile top-2 fold with u32 packed keys (verified round-10).
__global__ __launch_bounds__(256) void mfma_cand_kernel(
    const unsigned short* __restrict__ Ah,
    const unsigned short* __restrict__ Bh,
    unsigned* __restrict__ cand) {
  __shared__ alignas(16) char ldsA[16384];
  __shared__ alignas(16) char ldsB[16384];
  __shared__ unsigned topscr[128][2][2];

  const int tid = threadIdx.x, lane = tid & 63, w = tid >> 6;
  const int fr = lane & 15, g = lane >> 4;
  const int wr = (w >> 1) * 64, wc = (w & 1) * 64;
  const int bm = blockIdx.x, split = blockIdx.y;

  // staging descriptors: 4 issues per operand per K-step
  int srow[4], scol[4], soff[4];
#pragma unroll
  for (int i = 0; i < 4; ++i) {
    int s = i * 256 + w * 64 + lane;        // LDS 16B-slot index 0..1023
    int row = s >> 3, p = s & 7;
    srow[i] = row;
    scol[i] = (p ^ (row & 7)) * 8;          // source element offset (bf16)
    soff[i] = i * 4096 + w * 1024;          // wave-uniform LDS byte base
  }

  unsigned run1 = 0u, run2 = 0u;   // running per-row top-2 (tid<128 only)

  int tidx = 0;   // tile counter within split (0..12)
  for (int t = split; t < NT128; t += GSPLIT, ++tidx) {
    f32x4 acc[4][4];
#pragma unroll
    for (int m = 0; m < 4; ++m)
#pragma unroll
      for (int n = 0; n < 4; ++n) acc[m][n] = (f32x4){0.f, 0.f, 0.f, 0.f};

    const size_t abase = (size_t)bm * 128 * K_DIM;
    const size_t bbase = (size_t)t * 128 * K_DIM;

    for (int ks = 0; ks < K_DIM / 64; ++ks) {
      const int k0 = ks * 64;
      __syncthreads();
#pragma unroll
      for (int i = 0; i < 4; ++i) {
        gload16(Ah + abase + (size_t)srow[i] * K_DIM + k0 + scol[i], ldsA + soff[i]);
        gload16(Bh + bbase + (size_t)srow[i] * K_DIM + k0 + scol[i], ldsB + soff[i]);
      }
      __syncthreads();

      short8 af[4][2], bf[4][2];
#pragma unroll
      for (int m = 0; m < 4; ++m) {
        const int row = wr + m * 16 + fr;
#pragma unroll
        for (int k2 = 0; k2 < 2; ++k2) {
          const int p = (k2 * 4 + g) ^ (row & 7);
          af[m][k2] = *(const short8*)(ldsA + row * 128 + p * 16);
        }
      }
#pragma unroll
      for (int n = 0; n < 4; ++n) {
        const int row = wc + n * 16 + fr;
#pragma unroll
        for (int k2 = 0; k2 < 2; ++k2) {
          const int p = (k2 * 4 + g) ^ (row & 7);
          bf[n][k2] = *(const short8*)(ldsB + row * 128 + p * 16);
        }
      }
#pragma unroll
      for (int m = 0; m < 4; ++m)
#pragma unroll
        for (int n = 0; n < 4; ++n) {
          acc[m][n] = __builtin_amdgcn_mfma_f32_16x16x32_bf16(af[m][0], bf[n][0], acc[m][n], 0, 0, 0);
          acc[m][n] = __builtin_amdgcn_mfma_f32_16x16x32_bf16(af[m][1], bf[n][1], acc[m][n], 0, 0, 0);
        }
    }

    // per-tile top-2 per row, u32 keys; C/D: col=lane&15, row=g*4+j
    unsigned lowf[4];
#pragma unroll
    for (int n = 0; n < 4; ++n)
      lowf[n] = 2047u - (unsigned)(tidx * 128 + wc + n * 16 + fr);

#pragma unroll
    for (int m = 0; m < 4; ++m)
#pragma unroll
      for (int j = 0; j < 4; ++j) {
        unsigned p0 = (fkey(acc[m][0][j]) & 0xFFFFF800u) | lowf[0];
        unsigned p1 = (fkey(acc[m][1][j]) & 0xFFFFF800u) | lowf[1];
        unsigned p2 = (fkey(acc[m][2][j]) & 0xFFFFF800u) | lowf[2];
        unsigned p3 = (fkey(acc[m][3][j]) & 0xFFFFF800u) | lowf[3];
        unsigned a1 = umax32(p0, p1), a2 = umin32(p0, p1);
        unsigned b1 = umax32(p2, p3), b2 = umin32(p2, p3);
        unsigned t1 = umax32(a1, b1);
        unsigned t2 = umax32(umin32(a1, b1), umax32(a2, b2));
#pragma unroll
        for (int msk = 1; msk < 16; msk <<= 1) {
          unsigned o1 = (unsigned)__shfl_xor((int)t1, msk, 64);
          unsigned o2 = (unsigned)__shfl_xor((int)t2, msk, 64);
          if (o1 > t1) { t2 = umax32(t1, o2); t1 = o1; }
          else t2 = umax32(t2, o1);
        }
        if (fr == 0) {
          int rl = wr + m * 16 + g * 4 + j;
          topscr[rl][w & 1][0] = t1;
          topscr[rl][w & 1][1] = t2;
        }
      }
    __syncthreads();
    if (tid < 128) {
      unsigned a1 = topscr[tid][0][0], a2 = topscr[tid][0][1];
      unsigned b1 = topscr[tid][1][0], b2 = topscr[tid][1][1];
      unsigned m1, m2;
      if (a1 > b1) { m1 = a1; m2 = umax32(a2, b1); }
      else         { m1 = b1; m2 = umax32(b2, a1); }
      if (m1 > run1) { run2 = umax32(run1, m2); run1 = m1; }
      else run2 = umax32(run2, m1);
    }
  }

  if (tid < 128) {
    unsigned l1 = 2047u - (run1 & 0x7FFu);
    unsigned l2 = 2047u - (run2 & 0x7FFu);
    unsigned c1 = (unsigned)((split + (l1 >> 7) * GSPLIT) * 128) + (l1 & 127u);
    unsigned c2 = (unsigned)((split + (l2 >> 7) * GSPLIT) * 128) + (l2 & 127u);
    if (c1 >= V_DIM) c1 = 0;
    if (c2 >= V_DIM) c2 = 0;
    int grow = bm * 128 + tid;
    cand[(grow * GSPLIT + split) * 2 + 0] = c1;
    cand[(grow * GSPLIT + split) * 2 + 1] = c2;
  }
}

// fp32 rescore of 64 candidates/row, coalesced (verified rounds 11-13)
__global__ __launch_bounds__(256) void rescore_kernel(
    const float* __restrict__ noisy, const float* __restrict__ table,
    const unsigned* __restrict__ cand, u64* __restrict__ merged) {
  __shared__ u64 wbest[4];
  const int row = blockIdx.x;
  const int tid = threadIdx.x, lane = tid & 63, wv = tid >> 6;
  const float* a = noisy + (size_t)row * K_DIM + lane * 12;
  float4 a0 = *(const float4*)(a);
  float4 a1 = *(const float4*)(a + 4);
  float4 a2 = *(const float4*)(a + 8);

  u64 best = 0;
  for (int c = wv; c < NCAND; c += 4) {
    const unsigned ci = cand[row * NCAND + c];
    const float* b = table + (size_t)ci * K_DIM + lane * 12;
    float4 b0 = *(const float4*)(b);
    float4 b1 = *(const float4*)(b + 4);
    float4 b2 = *(const float4*)(b + 8);
    float s = 0.f;
    s = fmaf(a0.x, b0.x, s); s = fmaf(a0.y, b0.y, s);
    s = fmaf(a0.z, b0.z, s); s = fmaf(a0.w, b0.w, s);
    s = fmaf(a1.x, b1.x, s); s = fmaf(a1.y, b1.y, s);
    s = fmaf(a1.z, b1.z, s); s = fmaf(a1.w, b1.w, s);
    s = fmaf(a2.x, b2.x, s); s = fmaf(a2.y, b2.y, s);
    s = fmaf(a2.z, b2.z, s); s = fmaf(a2.w, b2.w, s);
#pragma unroll
    for (int m = 1; m < 64; m <<= 1) s += __shfl_xor(s, m, 64);
    u64 p = pack_maxidx(s, ci);
    if (p > best) best = p;
  }
  if (lane == 0) wbest[wv] = best;
  __syncthreads();
  if (tid == 0) {
    u64 b0_ = wbest[0], b1_ = wbest[1], b2_ = wbest[2], b3_ = wbest[3];
    u64 m01 = b0_ > b1_ ? b0_ : b1_;
    u64 m23 = b2_ > b3_ ? b2_ : b3_;
    merged[row] = m01 > m23 ? m01 : m23;
  }
}

// ============================ FALLBACK (verified round-6) ===================

__global__ void noise_add_kernel(const float* __restrict__ in,
                                 float* __restrict__ noisy,
                                 u64* __restrict__ merged) {
  const unsigned i = blockIdx.x * blockDim.x + threadIdx.x;
  if (i >= EMB_N) return;
  if (i < M_TOT) merged[i] = 0ull;
  unsigned x0 = 0u, x1 = i;
  threefry2x32_042(x0, x1);
  noisy[i] = in[i] + bits_to_noise(x0 ^ x1);
}

__global__ __launch_bounds__(256) void gemm_argmax_kernel(
    const float* __restrict__ noisy, const float* __restrict__ table,
    u64* __restrict__ merged) {
  __shared__ float As[16][132];
  __shared__ float Bs[16][132];
  __shared__ float redm[128][16];
  __shared__ int   redi[128][16];

  const int tid = threadIdx.x;
  const int lane = tid & 63;
  const int w = tid >> 6;
  const int tx = lane & 7, ty = lane >> 3;
  const int col0 = (w & 1) * 64 + tx * 8;
  const int row0 = (w >> 1) * 64 + ty * 8;
  const int bm = blockIdx.x;
  const int split = blockIdx.y;
  const float* Abase = noisy + (size_t)bm * 128 * K_DIM;

  float rmax[8]; int ridx[8];
#pragma unroll
  for (int r = 0; r < 8; ++r) { rmax[r] = -INFINITY; ridx[r] = 0x7FFFFFFF; }

  for (int t = split; t < NTILES; t += NSPLIT) {
    const int nbase = t * 128;
    float acc[8][8];
#pragma unroll
    for (int r = 0; r < 8; ++r)
#pragma unroll
      for (int c = 0; c < 8; ++c) acc[r][c] = 0.0f;

    for (int k0 = 0; k0 < K_DIM; k0 += 16) {
      __syncthreads();
#pragma unroll
      for (int l = 0; l < 2; ++l) {
        const int e = tid + l * 256;
        const int ml = e >> 2, kk = (e & 3) << 2;
        float4 av = *(const float4*)(Abase + (size_t)ml * K_DIM + k0 + kk);
        As[kk + 0][ml] = av.x; As[kk + 1][ml] = av.y;
        As[kk + 2][ml] = av.z; As[kk + 3][ml] = av.w;
        const int n = nbase + ml;
        float4 bv = make_float4(0.f, 0.f, 0.f, 0.f);
        if (n < V_DIM)
          bv = *(const float4*)(table + (size_t)n * K_DIM + k0 + kk);
        Bs[kk + 0][ml] = bv.x; Bs[kk + 1][ml] = bv.y;
        Bs[kk + 2][ml] = bv.z; Bs[kk + 3][ml] = bv.w;
      }
      __syncthreads();
#pragma unroll
      for (int k = 0; k < 16; ++k) {
        float4 a0 = *(const float4*)&As[k][row0];
        float4 a1 = *(const float4*)&As[k][row0 + 4];
        float4 b0 = *(const float4*)&Bs[k][col0];
        float4 b1 = *(const float4*)&Bs[k][col0 + 4];
        float a[8] = {a0.x, a0.y, a0.z, a0.w, a1.x, a1.y, a1.z, a1.w};
        float b[8] = {b0.x, b0.y, b0.z, b0.w, b1.x, b1.y, b1.z, b1.w};
#pragma unroll
        for (int r = 0; r < 8; ++r)
#pragma unroll
          for (int c = 0; c < 8; ++c)
            acc[r][c] = fmaf(a[r], b[c], acc[r][c]);
      }
    }
#pragma unroll
    for (int r = 0; r < 8; ++r)
#pragma unroll
      for (int c = 0; c < 8; ++c) {
        const int n = nbase + col0 + c;
        if (n < V_DIM && acc[r][c] > rmax[r]) { rmax[r] = acc[r][c]; ridx[r] = n; }
      }
  }

  __syncthreads();
#pragma unroll
  for (int r = 0; r < 8; ++r) {
    redm[row0 + r][(w & 1) * 8 + tx] = rmax[r];
    redi[row0 + r][(w & 1) * 8 + tx] = ridx[r];
  }
  __syncthreads();
  if (tid < 128) {
    float best = -INFINITY; int bi = 0x7FFFFFFF;
#pragma unroll
    for (int j = 0; j < 16; ++j) {
      float v = redm[tid][j]; int id = redi[tid][j];
      if (v > best || (v == best && id < bi)) { best = v; bi = id; }
    }
    atomicMax(&merged[bm * 128 + tid], pack_maxidx(best, (unsigned)bi));
  }
}

// ---------------- shared: unpack index + gather table row -------------------
__global__ void gather_kernel(const u64* __restrict__ merged,
                              const float* __restrict__ table,
                              float* __restrict__ out) {
  const int row = blockIdx.x;
  const int tid = threadIdx.x;
  const unsigned bi = 0xFFFFFFFFu - (unsigned)(merged[row] & 0xFFFFFFFFull);
  if (tid < 192) {
    float4 val = *(const float4*)(table + (size_t)bi * K_DIM + tid * 4);
    *(float4*)(out + (size_t)row * K_DIM + tid * 4) = val;
  }
}

// ---------------- launch ----------------
extern "C" void kernel_launch(void* const* d_in, const int* in_sizes, int n_in,
                              void* d_out, int out_size, void* d_ws, size_t ws_size,
                              hipStream_t stream) {
  const float* inputs = (const float*)d_in[0];
  const float* table  = (const float*)d_in[1];
  if (n_in >= 2 && (in_sizes[0] == TAB_N || in_sizes[1] == EMB_N)) {
    table  = (const float*)d_in[0];
    inputs = (const float*)d_in[1];
  }
  float* out = (float*)d_out;
  float* noisy = out;   // overwritten by gather at the end

  // fast-path ws layout (bytes)
  const size_t oAh = 0;
  const size_t oBh = oAh + (size_t)EMB_N * 2;            //  6,291,456
  const size_t oCand = oBh + (size_t)PADV * K_DIM * 2;   // 83,558,400
  const size_t oMerged = oCand + (size_t)M_TOT * NCAND * 4;
  const size_t REQ = oMerged + (size_t)M_TOT * 8;        // ~84.6 MB

  if (ws_size >= REQ) {
    unsigned short* Ah = (unsigned short*)((char*)d_ws + oAh);
    unsigned short* Bh = (unsigned short*)((char*)d_ws + oBh);
    unsigned* cand = (unsigned*)((char*)d_ws + oCand);
    u64* merged = (u64*)((char*)d_ws + oMerged);

    prep_kernel<<<NOISE_BLK + BSPLIT_BLK, 256, 0, stream>>>(inputs, table, noisy, Ah, Bh);
    dim3 g2(M_TOT / 128, GSPLIT);
    mfma_cand_kernel<<<g2, 256, 0, stream>>>(Ah, Bh, cand);
    rescore_kernel<<<M_TOT, 256, 0, stream>>>(noisy, table, cand, merged);
    gather_kernel<<<M_TOT, 256, 0, stream>>>(merged, table, out);
  } else {
    u64* merged = (u64*)d_ws;
    noise_add_kernel<<<EMB_N / 256, 256, 0, stream>>>(inputs, noisy, merged);
    dim3 g2(M_TOT / 128, NSPLIT);
    gemm_argmax_kernel<<<g2, 256, 0, stream>>>(noisy, table, merged);
    gather_kernel<<<M_TOT, 256, 0, stream>>>(merged, table, out);
  }
}

// Round 16
// 564.403 us; speedup vs baseline: 1.8871x; 1.0662x over previous
//
#include <hip/hip_runtime.h>
#include <hip/hip_bf16.h>
#include <float.h>
#include <math.h>

#define K_DIM 768
#define V_DIM 50257
#define M_TOT 4096
#define EMB_N 3145728            // 2*2048*768
#define TAB_N 38597376           // 50257*768
#define NT256 197                // N tiles of 256
#define PADV2 50432              // 197*256 padded vocab
#define GSPLIT 32                // N splits
#define NCAND 64                 // GSPLIT * top2
#define NSPLIT 16                // fallback fp32 kernel splits
#define NTILES ((V_DIM + 127) / 128)
#define NOISE_BLK (EMB_N / 256)                  // 12288
#define BSPLIT_BLK ((PADV2 * K_DIM / 4) / 256)   // 37824

typedef __attribute__((ext_vector_type(8))) short short8;
typedef __attribute__((ext_vector_type(4))) float f32x4;
typedef unsigned long long u64;

// ---------------- JAX threefry2x32 (key = (0, 42)), 20 rounds ----------------
__device__ __forceinline__ unsigned rotl32(unsigned v, int d) {
  return (v << d) | (v >> (32 - d));
}
__device__ __forceinline__ void threefry2x32_042(unsigned& x0, unsigned& x1) {
  const unsigned ks0 = 0u, ks1 = 42u;
  const unsigned ks2 = ks0 ^ ks1 ^ 0x1BD11BDAu;
  x0 += ks0; x1 += ks1;
#define TF_R(r) { x0 += x1; x1 = rotl32(x1, (r)); x1 ^= x0; }
  TF_R(13) TF_R(15) TF_R(26) TF_R(6)
  x0 += ks1; x1 += ks2 + 1u;
  TF_R(17) TF_R(29) TF_R(16) TF_R(24)
  x0 += ks2; x1 += ks0 + 2u;
  TF_R(13) TF_R(15) TF_R(26) TF_R(6)
  x0 += ks0; x1 += ks1 + 3u;
  TF_R(17) TF_R(29) TF_R(16) TF_R(24)
  x0 += ks1; x1 += ks2 + 4u;
  TF_R(13) TF_R(15) TF_R(26) TF_R(6)
  x0 += ks2; x1 += ks0 + 5u;
#undef TF_R
}

// bits -> uniform(-1+2^-24, 1) -> laplace -> /5  (exact JAX op sequence)
__device__ __forceinline__ float bits_to_noise(unsigned bits) {
  unsigned fb = (bits >> 9) | 0x3F800000u;
  float f = __uint_as_float(fb) - 1.0f;
  const float minv = -0.99999994039535522461f;
  float u = __fadd_rn(__fmul_rn(f, 2.0f), minv);
  u = fmaxf(minv, u);
  float s = (u > 0.0f) ? 1.0f : ((u < 0.0f) ? -1.0f : 0.0f);
  float l = s * log1pf(-fabsf(u));
  return __fdiv_rn(l, 5.0f);
}

__device__ __forceinline__ float bf2f(unsigned short b) {
  return __uint_as_float(((unsigned)b) << 16);
}
__device__ __forceinline__ unsigned short f2bf(float x) {
  __hip_bfloat16 h = __float2bfloat16(x);   // RNE
  return *(unsigned short*)&h;
}

// monotone u32 key of float (order-preserving)
__device__ __forceinline__ unsigned fkey(float v) {
  unsigned b = __float_as_uint(v);
  return b ^ (((unsigned)((int)b >> 31)) | 0x80000000u);
}
__device__ __forceinline__ u64 pack_maxidx(float v, unsigned idx) {
  return ((u64)fkey(v) << 32) | (u64)(0xFFFFFFFFu - idx);
}
__device__ __forceinline__ unsigned umax32(unsigned a, unsigned b) { return a > b ? a : b; }
__device__ __forceinline__ unsigned umin32(unsigned a, unsigned b) { return a < b ? a : b; }

__device__ __forceinline__ void gload16(const void* g, void* l) {
  __builtin_amdgcn_global_load_lds(
      (const __attribute__((address_space(1))) unsigned*)g,
      (__attribute__((address_space(3))) unsigned*)l, 16, 0, 0);
}

// ============================ FAST PATH ====================================

// fused prep: noisy(f32)->d_out + Ah bf16; table -> Bh bf16 (pad to PADV2)
__global__ void prep_kernel(const float* __restrict__ in,
                            const float* __restrict__ tab,
                            float* __restrict__ noisy,
                            unsigned short* __restrict__ Ah,
                            unsigned short* __restrict__ Bh) {
  if (blockIdx.x < NOISE_BLK) {
    const unsigned i = blockIdx.x * 256 + threadIdx.x;
    unsigned x0 = 0u, x1 = i;
    threefry2x32_042(x0, x1);
    float v = in[i] + bits_to_noise(x0 ^ x1);
    noisy[i] = v;
    Ah[i] = f2bf(v);
  } else {
    const size_t i = ((size_t)(blockIdx.x - NOISE_BLK) * 256 + threadIdx.x) * 4;
    ushort4 h;
    if (i < (size_t)TAB_N) {
      float4 v = *(const float4*)(tab + i);
      h.x = f2bf(v.x); h.y = f2bf(v.y); h.z = f2bf(v.z); h.w = f2bf(v.w);
    } else {
      h = make_ushort4(0, 0, 0, 0);
    }
    *(ushort4*)(Bh + i) = h;
  }
}

// 256x256-tile, 8-wave bf16 MFMA GEMM with counted-vmcnt double-buffer.
// Per K-tile (BK=64): vmcnt(8) [waits only the 8 loads staged 2 K-tiles ago;
// 8 newer stay in flight] + s_barrier; 32 ds_read + 64 MFMA per wave;
// lgkmcnt(0) + s_barrier; STAGE(kt+2 -> just-read buf) [WAR-safe].
// Never drains vmcnt to 0 in the K-loop (T4); per-tile fold's __syncthreads
// provides the one covered drain. LDS: A0@0 B0@32K A1@64K B1@96K (128KB) +
// topscr 8KB. Rows 128B, slot swizzle p = q ^ (row&7) on both sides (r10).
__global__ __launch_bounds__(512, 2) void mfma_cand_kernel(
    const unsigned short* __restrict__ Ah,
    const unsigned short* __restrict__ Bh,
    unsigned* __restrict__ cand) {
  __shared__ alignas(16) char lds[131072];
  __shared__ unsigned topscr[256][4][2];

  const int tid = threadIdx.x;
  const int lane = tid & 63, w = tid >> 6;
  const int fr = lane & 15, g = lane >> 4;
  const int WM = w >> 2, WN = w & 3;       // 2 x 4 wave grid
  const int wr = WM * 128, wc = WN * 64;   // wave tile: 128 rows x 64 cols
  const int bm = blockIdx.x, split = blockIdx.y;

  // staging descriptors: 4 iters x 512 thr x 16B = 32KB per operand/K-tile
  int srowv[4], scolv[4], soffv[4];
#pragma unroll
  for (int i = 0; i < 4; ++i) {
    int s = i * 512 + tid;                 // 16B-slot 0..2047
    int row = s >> 3, p = s & 7;           // 8 slots (128B) per row
    srowv[i] = row;
    scolv[i] = (p ^ (row & 7)) * 8;        // pre-swizzled source elem offset
    soffv[i] = i * 8192 + w * 1024;        // wave-uniform LDS byte base
  }

  const size_t abase = (size_t)bm * 256 * K_DIM;

#define STAGE(buf, bb, kofs) do {                                              \
    _Pragma("unroll")                                                          \
    for (int i_ = 0; i_ < 4; ++i_) {                                           \
      gload16(Ah + abase + (size_t)srowv[i_] * K_DIM + (kofs) + scolv[i_],     \
              lds + (buf) * 65536 + soffv[i_]);                                \
      gload16(Bh + (bb) + (size_t)srowv[i_] * K_DIM + (kofs) + scolv[i_],      \
              lds + (buf) * 65536 + 32768 + soffv[i_]);                        \
    } } while (0)

  unsigned run1 = 0u, run2 = 0u;   // running per-row top-2 (tid<256 only)

  // prologue: stage K-tiles 0 and 1 of the first tile (16 loads in flight)
  {
    const size_t bb0 = (size_t)split * 256 * K_DIM;
    STAGE(0, bb0, 0);
    STAGE(1, bb0, 64);
  }

  int tidx = 0;   // tile counter within split (0..6)
  for (int t = split; t < NT256; t += GSPLIT, ++tidx) {
    f32x4 acc[8][4];
#pragma unroll
    for (int m = 0; m < 8; ++m)
#pragma unroll
      for (int n = 0; n < 4; ++n) acc[m][n] = (f32x4){0.f, 0.f, 0.f, 0.f};

    const size_t bbase = (size_t)t * 256 * K_DIM;
    const int tnext = (t + GSPLIT < NT256) ? (t + GSPLIT) : t;  // clamp: last
    const size_t bnext = (size_t)tnext * 256 * K_DIM;           // tile stages
                                                                // dummy data
    for (int kt = 0; kt < K_DIM / 64; ++kt) {
      // wait ONLY the 8 loads of this K-tile (issued 2 K-tiles ago);
      // the 8 newer loads stay in flight across the barrier (T4).
      asm volatile("s_waitcnt vmcnt(8)" ::: "memory");
      __builtin_amdgcn_s_barrier();
      __builtin_amdgcn_sched_barrier(0);

      const char* lA = lds + (kt & 1) * 65536;
      const char* lB = lA + 32768;
#pragma unroll
      for (int kh = 0; kh < 2; ++kh) {
        short8 bfv[4];
#pragma unroll
        for (int n = 0; n < 4; ++n) {
          const int row = wc + n * 16 + fr;
          const int p = (kh * 4 + g) ^ (row & 7);
          bfv[n] = *(const short8*)(lB + row * 128 + p * 16);
        }
#pragma unroll
        for (int mh = 0; mh < 2; ++mh) {
          short8 afv[4];
#pragma unroll
          for (int mi = 0; mi < 4; ++mi) {
            const int row = wr + (mh * 4 + mi) * 16 + fr;
            const int p = (kh * 4 + g) ^ (row & 7);
            afv[mi] = *(const short8*)(lA + row * 128 + p * 16);
          }
#pragma unroll
          for (int mi = 0; mi < 4; ++mi)
#pragma unroll
            for (int n = 0; n < 4; ++n)
              acc[mh * 4 + mi][n] = __builtin_amdgcn_mfma_f32_16x16x32_bf16(
                  afv[mi], bfv[n], acc[mh * 4 + mi][n], 0, 0, 0);
        }
      }

      asm volatile("s_waitcnt lgkmcnt(0)" ::: "memory");
      __builtin_amdgcn_s_barrier();        // all waves done reading this buf
      __builtin_amdgcn_sched_barrier(0);

      // refill the just-read buffer with K-tile kt+2 (next tile if kt>=10)
      const int kn = kt + 2;
      if (kn < K_DIM / 64) {
        STAGE(kt & 1, bbase, kn * 64);
      } else {
        STAGE(kt & 1, bnext, (kn - K_DIM / 64) * 64);
      }
    }

    // ---- per-tile fold: per-row top-2 over 256 cols (u32 packed keys) ----
    __syncthreads();   // drains vmcnt (next tile's kt0/kt1 land under fold)
    unsigned lowf[4];
#pragma unroll
    for (int n = 0; n < 4; ++n)
      lowf[n] = 2047u - (unsigned)(tidx * 256 + wc + n * 16 + fr);

#pragma unroll
    for (int m = 0; m < 8; ++m)
#pragma unroll
      for (int j = 0; j < 4; ++j) {
        unsigned p0 = (fkey(acc[m][0][j]) & 0xFFFFF800u) | lowf[0];
        unsigned p1 = (fkey(acc[m][1][j]) & 0xFFFFF800u) | lowf[1];
        unsigned p2 = (fkey(acc[m][2][j]) & 0xFFFFF800u) | lowf[2];
        unsigned p3 = (fkey(acc[m][3][j]) & 0xFFFFF800u) | lowf[3];
        unsigned a1 = umax32(p0, p1), a2 = umin32(p0, p1);
        unsigned b1 = umax32(p2, p3), b2 = umin32(p2, p3);
        unsigned t1 = umax32(a1, b1);
        unsigned t2 = umax32(umin32(a1, b1), umax32(a2, b2));
#pragma unroll
        for (int msk = 1; msk < 16; msk <<= 1) {
          unsigned o1 = (unsigned)__shfl_xor((int)t1, msk, 64);
          unsigned o2 = (unsigned)__shfl_xor((int)t2, msk, 64);
          if (o1 > t1) { t2 = umax32(t1, o2); t1 = o1; }
          else t2 = umax32(t2, o1);
        }
        if (fr == 0) {
          int rl = wr + m * 16 + g * 4 + j;   // 0..255
          topscr[rl][WN][0] = t1;
          topscr[rl][WN][1] = t2;
        }
      }
    __syncthreads();
    if (tid < 256) {
      unsigned m1 = topscr[tid][0][0], m2 = topscr[tid][0][1];
#pragma unroll
      for (int q = 1; q < 4; ++q) {
        unsigned c1 = topscr[tid][q][0], c2 = topscr[tid][q][1];
        if (c1 > m1) { m2 = umax32(m1, c2); m1 = c1; }
        else m2 = umax32(m2, c1);
      }
      if (m1 > run1) { run2 = umax32(run1, m2); run1 = m1; }
      else run2 = umax32(run2, m1);
    }
  }
#undef STAGE

  if (tid < 256) {
    unsigned l1 = 2047u - (run1 & 0x7FFu);
    unsigned l2 = 2047u - (run2 & 0x7FFu);
    unsigned c1 = (unsigned)((split + (l1 >> 8) * GSPLIT) * 256) + (l1 & 255u);
    unsigned c2 = (unsigned)((split + (l2 >> 8) * GSPLIT) * 256) + (l2 & 255u);
    if (c1 >= V_DIM) c1 = 0;
    if (c2 >= V_DIM) c2 = 0;
    int grow = bm * 256 + tid;
    cand[(grow * GSPLIT + split) * 2 + 0] = c1;
    cand[(grow * GSPLIT + split) * 2 + 1] = c2;
  }
}

// fp32 rescore of 64 candidates/row, coalesced (verified rounds 11-15)
__global__ __launch_bounds__(256) void rescore_kernel(
    const float* __restrict__ noisy, const float* __restrict__ table,
    const unsigned* __restrict__ cand, u64* __restrict__ merged) {
  __shared__ u64 wbest[4];
  const int row = blockIdx.x;
  const int tid = threadIdx.x, lane = tid & 63, wv = tid >> 6;
  const float* a = noisy + (size_t)row * K_DIM + lane * 12;
  float4 a0 = *(const float4*)(a);
  float4 a1 = *(const float4*)(a + 4);
  float4 a2 = *(const float4*)(a + 8);

  u64 best = 0;
  for (int c = wv; c < NCAND; c += 4) {
    const unsigned ci = cand[row * NCAND + c];
    const float* b = table + (size_t)ci * K_DIM + lane * 12;
    float4 b0 = *(const float4*)(b);
    float4 b1 = *(const float4*)(b + 4);
    float4 b2 = *(const float4*)(b + 8);
    float s = 0.f;
    s = fmaf(a0.x, b0.x, s); s = fmaf(a0.y, b0.y, s);
    s = fmaf(a0.z, b0.z, s); s = fmaf(a0.w, b0.w, s);
    s = fmaf(a1.x, b1.x, s); s = fmaf(a1.y, b1.y, s);
    s = fmaf(a1.z, b1.z, s); s = fmaf(a1.w, b1.w, s);
    s = fmaf(a2.x, b2.x, s); s = fmaf(a2.y, b2.y, s);
    s = fmaf(a2.z, b2.z, s); s = fmaf(a2.w, b2.w, s);
#pragma unroll
    for (int m = 1; m < 64; m <<= 1) s += __shfl_xor(s, m, 64);
    u64 p = pack_maxidx(s, ci);
    if (p > best) best = p;
  }
  if (lane == 0) wbest[wv] = best;
  __syncthreads();
  if (tid == 0) {
    u64 b0_ = wbest[0], b1_ = wbest[1], b2_ = wbest[2], b3_ = wbest[3];
    u64 m01 = b0_ > b1_ ? b0_ : b1_;
    u64 m23 = b2_ > b3_ ? b2_ : b3_;
    merged[row] = m01 > m23 ? m01 : m23;
  }
}

// ============================ FALLBACK (verified round-6) ===================

__global__ void noise_add_kernel(const float* __restrict__ in,
                                 float* __restrict__ noisy,
                                 u64* __restrict__ merged) {
  const unsigned i = blockIdx.x * blockDim.x + threadIdx.x;
  if (i >= EMB_N) return;
  if (i < M_TOT) merged[i] = 0ull;
  unsigned x0 = 0u, x1 = i;
  threefry2x32_042(x0, x1);
  noisy[i] = in[i] + bits_to_noise(x0 ^ x1);
}

__global__ __launch_bounds__(256) void gemm_argmax_kernel(
    const float* __restrict__ noisy, const float* __restrict__ table,
    u64* __restrict__ merged) {
  __shared__ float As[16][132];
  __shared__ float Bs[16][132];
  __shared__ float redm[128][16];
  __shared__ int   redi[128][16];

  const int tid = threadIdx.x;
  const int lane = tid & 63;
  const int w = tid >> 6;
  const int tx = lane & 7, ty = lane >> 3;
  const int col0 = (w & 1) * 64 + tx * 8;
  const int row0 = (w >> 1) * 64 + ty * 8;
  const int bm = blockIdx.x;
  const int split = blockIdx.y;
  const float* Abase = noisy + (size_t)bm * 128 * K_DIM;

  float rmax[8]; int ridx[8];
#pragma unroll
  for (int r = 0; r < 8; ++r) { rmax[r] = -INFINITY; ridx[r] = 0x7FFFFFFF; }

  for (int t = split; t < NTILES; t += NSPLIT) {
    const int nbase = t * 128;
    float acc[8][8];
#pragma unroll
    for (int r = 0; r < 8; ++r)
#pragma unroll
      for (int c = 0; c < 8; ++c) acc[r][c] = 0.0f;

    for (int k0 = 0; k0 < K_DIM; k0 += 16) {
      __syncthreads();
#pragma unroll
      for (int l = 0; l < 2; ++l) {
        const int e = tid + l * 256;
        const int ml = e >> 2, kk = (e & 3) << 2;
        float4 av = *(const float4*)(Abase + (size_t)ml * K_DIM + k0 + kk);
        As[kk + 0][ml] = av.x; As[kk + 1][ml] = av.y;
        As[kk + 2][ml] = av.z; As[kk + 3][ml] = av.w;
        const int n = nbase + ml;
        float4 bv = make_float4(0.f, 0.f, 0.f, 0.f);
        if (n < V_DIM)
          bv = *(const float4*)(table + (size_t)n * K_DIM + k0 + kk);
        Bs[kk + 0][ml] = bv.x; Bs[kk + 1][ml] = bv.y;
        Bs[kk + 2][ml] = bv.z; Bs[kk + 3][ml] = bv.w;
      }
      __syncthreads();
#pragma unroll
      for (int k = 0; k < 16; ++k) {
        float4 a0 = *(const float4*)&As[k][row0];
        float4 a1 = *(const float4*)&As[k][row0 + 4];
        float4 b0 = *(const float4*)&Bs[k][col0];
        float4 b1 = *(const float4*)&Bs[k][col0 + 4];
        float a[8] = {a0.x, a0.y, a0.z, a0.w, a1.x, a1.y, a1.z, a1.w};
        float b[8] = {b0.x, b0.y, b0.z, b0.w, b1.x, b1.y, b1.z, b1.w};
#pragma unroll
        for (int r = 0; r < 8; ++r)
#pragma unroll
          for (int c = 0; c < 8; ++c)
            acc[r][c] = fmaf(a[r], b[c], acc[r][c]);
      }
    }
#pragma unroll
    for (int r = 0; r < 8; ++r)
#pragma unroll
      for (int c = 0; c < 8; ++c) {
        const int n = nbase + col0 + c;
        if (n < V_DIM && acc[r][c] > rmax[r]) { rmax[r] = acc[r][c]; ridx[r] = n; }
      }
  }

  __syncthreads();
#pragma unroll
  for (int r = 0; r < 8; ++r) {
    redm[row0 + r][(w & 1) * 8 + tx] = rmax[r];
    redi[row0 + r][(w & 1) * 8 + tx] = ridx[r];
  }
  __syncthreads();
  if (tid < 128) {
    float best = -INFINITY; int bi = 0x7FFFFFFF;
#pragma unroll
    for (int j = 0; j < 16; ++j) {
      float v = redm[tid][j]; int id = redi[tid][j];
      if (v > best || (v == best && id < bi)) { best = v; bi = id; }
    }
    atomicMax(&merged[bm * 128 + tid], pack_maxidx(best, (unsigned)bi));
  }
}

// ---------------- shared: unpack index + gather table row -------------------
__global__ void gather_kernel(const u64* __restrict__ merged,
                              const float* __restrict__ table,
                              float* __restrict__ out) {
  const int row = blockIdx.x;
  const int tid = threadIdx.x;
  const unsigned bi = 0xFFFFFFFFu - (unsigned)(merged[row] & 0xFFFFFFFFull);
  if (tid < 192) {
    float4 val = *(const float4*)(table + (size_t)bi * K_DIM + tid * 4);
    *(float4*)(out + (size_t)row * K_DIM + tid * 4) = val;
  }
}

// ---------------- launch ----------------
extern "C" void kernel_launch(void* const* d_in, const int* in_sizes, int n_in,
                              void* d_out, int out_size, void* d_ws, size_t ws_size,
                              hipStream_t stream) {
  const float* inputs = (const float*)d_in[0];
  const float* table  = (const float*)d_in[1];
  if (n_in >= 2 && (in_sizes[0] == TAB_N || in_sizes[1] == EMB_N)) {
    table  = (const float*)d_in[0];
    inputs = (const float*)d_in[1];
  }
  float* out = (float*)d_out;
  float* noisy = out;   // overwritten by gather at the end

  // fast-path ws layout (bytes)
  const size_t oAh = 0;
  const size_t oBh = oAh + (size_t)EMB_N * 2;             //  6,291,456
  const size_t oCand = oBh + (size_t)PADV2 * K_DIM * 2;   // 83,755,008
  const size_t oMerged = oCand + (size_t)M_TOT * NCAND * 4;
  const size_t REQ = oMerged + (size_t)M_TOT * 8;         // ~84.9 MB

  if (ws_size >= REQ) {
    unsigned short* Ah = (unsigned short*)((char*)d_ws + oAh);
    unsigned short* Bh = (unsigned short*)((char*)d_ws + oBh);
    unsigned* cand = (unsigned*)((char*)d_ws + oCand);
    u64* merged = (u64*)((char*)d_ws + oMerged);

    prep_kernel<<<NOISE_BLK + BSPLIT_BLK, 256, 0, stream>>>(inputs, table, noisy, Ah, Bh);
    dim3 g2(M_TOT / 256, GSPLIT);   // 16 x 32 = 512 blocks, 1/CU
    mfma_cand_kernel<<<g2, 512, 0, stream>>>(Ah, Bh, cand);
    rescore_kernel<<<M_TOT, 256, 0, stream>>>(noisy, table, cand, merged);
    gather_kernel<<<M_TOT, 256, 0, stream>>>(merged, table, out);
  } else {
    u64* merged = (u64*)d_ws;
    noise_add_kernel<<<EMB_N / 256, 256, 0, stream>>>(inputs, noisy, merged);
    dim3 g2(M_TOT / 128, NSPLIT);
    gemm_argmax_kernel<<<g2, 256, 0, stream>>>(noisy, table, merged);
    gather_kernel<<<M_TOT, 256, 0, stream>>>(merged, table, out);
  }
}

// Round 17
// 485.440 us; speedup vs baseline: 2.1941x; 1.1627x over previous
//
#include <hip/hip_runtime.h>
#include <hip/hip_bf16.h>
#include <float.h>
#include <math.h>

#define K_DIM 768
#define V_DIM 50257
#define M_TOT 4096
#define EMB_N 3145728            // 2*2048*768
#define TAB_N 38597376           // 50257*768
#define NT256 197                // N tiles of 256
#define PADV2 50432              // 197*256 padded vocab
#define GSPLIT 32                // N splits
#define NCAND 64                 // GSPLIT * top2
#define NSPLIT 16                // fallback fp32 kernel splits
#define NTILES ((V_DIM + 127) / 128)
#define NOISE_BLK (EMB_N / 256)                  // 12288
#define BSPLIT_BLK ((PADV2 * K_DIM / 4) / 256)   // 37824

typedef __attribute__((ext_vector_type(8))) short short8;
typedef __attribute__((ext_vector_type(4))) float f32x4;
typedef unsigned long long u64;

// ---------------- JAX threefry2x32 (key = (0, 42)), 20 rounds ----------------
__device__ __forceinline__ unsigned rotl32(unsigned v, int d) {
  return (v << d) | (v >> (32 - d));
}
__device__ __forceinline__ void threefry2x32_042(unsigned& x0, unsigned& x1) {
  const unsigned ks0 = 0u, ks1 = 42u;
  const unsigned ks2 = ks0 ^ ks1 ^ 0x1BD11BDAu;
  x0 += ks0; x1 += ks1;
#define TF_R(r) { x0 += x1; x1 = rotl32(x1, (r)); x1 ^= x0; }
  TF_R(13) TF_R(15) TF_R(26) TF_R(6)
  x0 += ks1; x1 += ks2 + 1u;
  TF_R(17) TF_R(29) TF_R(16) TF_R(24)
  x0 += ks2; x1 += ks0 + 2u;
  TF_R(13) TF_R(15) TF_R(26) TF_R(6)
  x0 += ks0; x1 += ks1 + 3u;
  TF_R(17) TF_R(29) TF_R(16) TF_R(24)
  x0 += ks1; x1 += ks2 + 4u;
  TF_R(13) TF_R(15) TF_R(26) TF_R(6)
  x0 += ks2; x1 += ks0 + 5u;
#undef TF_R
}

// bits -> uniform(-1+2^-24, 1) -> laplace -> /5  (exact JAX op sequence)
__device__ __forceinline__ float bits_to_noise(unsigned bits) {
  unsigned fb = (bits >> 9) | 0x3F800000u;
  float f = __uint_as_float(fb) - 1.0f;
  const float minv = -0.99999994039535522461f;
  float u = __fadd_rn(__fmul_rn(f, 2.0f), minv);
  u = fmaxf(minv, u);
  float s = (u > 0.0f) ? 1.0f : ((u < 0.0f) ? -1.0f : 0.0f);
  float l = s * log1pf(-fabsf(u));
  return __fdiv_rn(l, 5.0f);
}

__device__ __forceinline__ float bf2f(unsigned short b) {
  return __uint_as_float(((unsigned)b) << 16);
}
__device__ __forceinline__ unsigned short f2bf(float x) {
  __hip_bfloat16 h = __float2bfloat16(x);   // RNE
  return *(unsigned short*)&h;
}

// monotone u32 key of float (order-preserving)
__device__ __forceinline__ unsigned fkey(float v) {
  unsigned b = __float_as_uint(v);
  return b ^ (((unsigned)((int)b >> 31)) | 0x80000000u);
}
__device__ __forceinline__ u64 pack_maxidx(float v, unsigned idx) {
  return ((u64)fkey(v) << 32) | (u64)(0xFFFFFFFFu - idx);
}
__device__ __forceinline__ unsigned umax32(unsigned a, unsigned b) { return a > b ? a : b; }
__device__ __forceinline__ unsigned umin32(unsigned a, unsigned b) { return a < b ? a : b; }

__device__ __forceinline__ void gload16(const void* g, void* l) {
  __builtin_amdgcn_global_load_lds(
      (const __attribute__((address_space(1))) unsigned*)g,
      (__attribute__((address_space(3))) unsigned*)l, 16, 0, 0);
}

// ============================ FAST PATH ====================================

// fused prep: noisy(f32)->d_out + Ah bf16; table -> Bh bf16 (pad to PADV2)
__global__ void prep_kernel(const float* __restrict__ in,
                            const float* __restrict__ tab,
                            float* __restrict__ noisy,
                            unsigned short* __restrict__ Ah,
                            unsigned short* __restrict__ Bh) {
  if (blockIdx.x < NOISE_BLK) {
    const unsigned i = blockIdx.x * 256 + threadIdx.x;
    unsigned x0 = 0u, x1 = i;
    threefry2x32_042(x0, x1);
    float v = in[i] + bits_to_noise(x0 ^ x1);
    noisy[i] = v;
    Ah[i] = f2bf(v);
  } else {
    const size_t i = ((size_t)(blockIdx.x - NOISE_BLK) * 256 + threadIdx.x) * 4;
    ushort4 h;
    if (i < (size_t)TAB_N) {
      float4 v = *(const float4*)(tab + i);
      h.x = f2bf(v.x); h.y = f2bf(v.y); h.z = f2bf(v.z); h.w = f2bf(v.w);
    } else {
      h = make_ushort4(0, 0, 0, 0);
    }
    *(ushort4*)(Bh + i) = h;
  }
}

// 256x256-tile, 8-wave bf16 MFMA GEMM, counted-vmcnt double-buffer (r16) +
// DEFERRED-REGISTER fold: running per-thread top-2 r1/r2[8][4] (u32 keys)
// across ALL tiles; cross-lane butterfly + topscr merge happens ONCE at the
// end. No per-tile barriers/shfl/LDS in the fold; K-loop pipeline is
// seamless across tiles. VGPR is free here: LDS (136KB) caps at 1 block/CU.
__global__ __launch_bounds__(512, 2) void mfma_cand_kernel(
    const unsigned short* __restrict__ Ah,
    const unsigned short* __restrict__ Bh,
    unsigned* __restrict__ cand) {
  __shared__ alignas(16) char lds[131072];
  __shared__ unsigned topscr[256][4][2];

  const int tid = threadIdx.x;
  const int lane = tid & 63, w = tid >> 6;
  const int fr = lane & 15, g = lane >> 4;
  const int WM = w >> 2, WN = w & 3;       // 2 x 4 wave grid
  const int wr = WM * 128, wc = WN * 64;   // wave tile: 128 rows x 64 cols
  const int bm = blockIdx.x, split = blockIdx.y;

  // staging descriptors: 4 iters x 512 thr x 16B = 32KB per operand/K-tile
  int srowv[4], scolv[4], soffv[4];
#pragma unroll
  for (int i = 0; i < 4; ++i) {
    int s = i * 512 + tid;                 // 16B-slot 0..2047
    int row = s >> 3, p = s & 7;           // 8 slots (128B) per row
    srowv[i] = row;
    scolv[i] = (p ^ (row & 7)) * 8;        // pre-swizzled source elem offset
    soffv[i] = i * 8192 + w * 1024;        // wave-uniform LDS byte base
  }

  const size_t abase = (size_t)bm * 256 * K_DIM;

#define STAGE(buf, bb, kofs) do {                                              \
    _Pragma("unroll")                                                          \
    for (int i_ = 0; i_ < 4; ++i_) {                                           \
      gload16(Ah + abase + (size_t)srowv[i_] * K_DIM + (kofs) + scolv[i_],     \
              lds + (buf) * 65536 + soffv[i_]);                                \
      gload16(Bh + (bb) + (size_t)srowv[i_] * K_DIM + (kofs) + scolv[i_],      \
              lds + (buf) * 65536 + 32768 + soffv[i_]);                        \
    } } while (0)

  // deferred per-thread running top-2 per (m,j), u32 packed keys
  unsigned r1[8][4], r2[8][4];
#pragma unroll
  for (int m = 0; m < 8; ++m)
#pragma unroll
    for (int j = 0; j < 4; ++j) { r1[m][j] = 0u; r2[m][j] = 0u; }

  // prologue: stage K-tiles 0 and 1 of the first tile (16 loads in flight)
  {
    const size_t bb0 = (size_t)split * 256 * K_DIM;
    STAGE(0, bb0, 0);
    STAGE(1, bb0, 64);
  }

  int tidx = 0;   // tile counter within split (0..6)
  for (int t = split; t < NT256; t += GSPLIT, ++tidx) {
    f32x4 acc[8][4];
#pragma unroll
    for (int m = 0; m < 8; ++m)
#pragma unroll
      for (int n = 0; n < 4; ++n) acc[m][n] = (f32x4){0.f, 0.f, 0.f, 0.f};

    const size_t bbase = (size_t)t * 256 * K_DIM;
    const int tnext = (t + GSPLIT < NT256) ? (t + GSPLIT) : t;  // clamp: last
    const size_t bnext = (size_t)tnext * 256 * K_DIM;           // stages dummy

    for (int kt = 0; kt < K_DIM / 64; ++kt) {
      // wait ONLY the 8 loads of this K-tile (issued 2 K-tiles ago);
      // the 8 newer loads stay in flight across the barrier (T4).
      asm volatile("s_waitcnt vmcnt(8)" ::: "memory");
      __builtin_amdgcn_s_barrier();
      __builtin_amdgcn_sched_barrier(0);

      const char* lA = lds + (kt & 1) * 65536;
      const char* lB = lA + 32768;
#pragma unroll
      for (int kh = 0; kh < 2; ++kh) {
        short8 bfv[4];
#pragma unroll
        for (int n = 0; n < 4; ++n) {
          const int row = wc + n * 16 + fr;
          const int p = (kh * 4 + g) ^ (row & 7);
          bfv[n] = *(const short8*)(lB + row * 128 + p * 16);
        }
#pragma unroll
        for (int mh = 0; mh < 2; ++mh) {
          short8 afv[4];
#pragma unroll
          for (int mi = 0; mi < 4; ++mi) {
            const int row = wr + (mh * 4 + mi) * 16 + fr;
            const int p = (kh * 4 + g) ^ (row & 7);
            afv[mi] = *(const short8*)(lA + row * 128 + p * 16);
          }
#pragma unroll
          for (int mi = 0; mi < 4; ++mi)
#pragma unroll
            for (int n = 0; n < 4; ++n)
              acc[mh * 4 + mi][n] = __builtin_amdgcn_mfma_f32_16x16x32_bf16(
                  afv[mi], bfv[n], acc[mh * 4 + mi][n], 0, 0, 0);
        }
      }

      asm volatile("s_waitcnt lgkmcnt(0)" ::: "memory");
      __builtin_amdgcn_s_barrier();        // all waves done reading this buf
      __builtin_amdgcn_sched_barrier(0);

      // refill the just-read buffer with K-tile kt+2 (next tile if kt>=10)
      const int kn = kt + 2;
      if (kn < K_DIM / 64) {
        STAGE(kt & 1, bbase, kn * 64);
      } else {
        STAGE(kt & 1, bnext, (kn - K_DIM / 64) * 64);
      }
    }

    // ---- per-tile fold into running registers (no barriers, no shfl) ----
    unsigned lowf[4];
#pragma unroll
    for (int n = 0; n < 4; ++n)
      lowf[n] = 2047u - (unsigned)(tidx * 256 + wc + n * 16 + fr);

#pragma unroll
    for (int m = 0; m < 8; ++m)
#pragma unroll
      for (int j = 0; j < 4; ++j) {
        unsigned p0 = (fkey(acc[m][0][j]) & 0xFFFFF800u) | lowf[0];
        unsigned p1 = (fkey(acc[m][1][j]) & 0xFFFFF800u) | lowf[1];
        unsigned p2 = (fkey(acc[m][2][j]) & 0xFFFFF800u) | lowf[2];
        unsigned p3 = (fkey(acc[m][3][j]) & 0xFFFFF800u) | lowf[3];
        unsigned a1 = umax32(p0, p1), a2 = umin32(p0, p1);
        unsigned b1 = umax32(p2, p3), b2 = umin32(p2, p3);
        unsigned t1 = umax32(a1, b1);
        unsigned t2 = umax32(umin32(a1, b1), umax32(a2, b2));
        if (t1 > r1[m][j]) { r2[m][j] = umax32(r1[m][j], t2); r1[m][j] = t1; }
        else r2[m][j] = umax32(r2[m][j], t1);
      }
  }
#undef STAGE

  // ---- ONE cross-lane butterfly + topscr merge at the end ----
#pragma unroll
  for (int m = 0; m < 8; ++m)
#pragma unroll
    for (int j = 0; j < 4; ++j) {
      unsigned t1 = r1[m][j], t2 = r2[m][j];
#pragma unroll
      for (int msk = 1; msk < 16; msk <<= 1) {
        unsigned o1 = (unsigned)__shfl_xor((int)t1, msk, 64);
        unsigned o2 = (unsigned)__shfl_xor((int)t2, msk, 64);
        if (o1 > t1) { t2 = umax32(t1, o2); t1 = o1; }
        else t2 = umax32(t2, o1);
      }
      if (fr == 0) {
        int rl = wr + m * 16 + g * 4 + j;   // 0..255
        topscr[rl][WN][0] = t1;
        topscr[rl][WN][1] = t2;
      }
    }
  __syncthreads();

  if (tid < 256) {
    unsigned m1 = topscr[tid][0][0], m2 = topscr[tid][0][1];
#pragma unroll
    for (int q = 1; q < 4; ++q) {
      unsigned c1 = topscr[tid][q][0], c2 = topscr[tid][q][1];
      if (c1 > m1) { m2 = umax32(m1, c2); m1 = c1; }
      else m2 = umax32(m2, c1);
    }
    unsigned l1 = 2047u - (m1 & 0x7FFu);
    unsigned l2 = 2047u - (m2 & 0x7FFu);
    unsigned c1 = (unsigned)((split + (l1 >> 8) * GSPLIT) * 256) + (l1 & 255u);
    unsigned c2 = (unsigned)((split + (l2 >> 8) * GSPLIT) * 256) + (l2 & 255u);
    if (c1 >= V_DIM) c1 = 0;
    if (c2 >= V_DIM) c2 = 0;
    int grow = bm * 256 + tid;
    cand[(grow * GSPLIT + split) * 2 + 0] = c1;
    cand[(grow * GSPLIT + split) * 2 + 1] = c2;
  }
}

// fp32 rescore of 64 candidates/row, coalesced (verified rounds 11-16)
__global__ __launch_bounds__(256) void rescore_kernel(
    const float* __restrict__ noisy, const float* __restrict__ table,
    const unsigned* __restrict__ cand, u64* __restrict__ merged) {
  __shared__ u64 wbest[4];
  const int row = blockIdx.x;
  const int tid = threadIdx.x, lane = tid & 63, wv = tid >> 6;
  const float* a = noisy + (size_t)row * K_DIM + lane * 12;
  float4 a0 = *(const float4*)(a);
  float4 a1 = *(const float4*)(a + 4);
  float4 a2 = *(const float4*)(a + 8);

  u64 best = 0;
  for (int c = wv; c < NCAND; c += 4) {
    const unsigned ci = cand[row * NCAND + c];
    const float* b = table + (size_t)ci * K_DIM + lane * 12;
    float4 b0 = *(const float4*)(b);
    float4 b1 = *(const float4*)(b + 4);
    float4 b2 = *(const float4*)(b + 8);
    float s = 0.f;
    s = fmaf(a0.x, b0.x, s); s = fmaf(a0.y, b0.y, s);
    s = fmaf(a0.z, b0.z, s); s = fmaf(a0.w, b0.w, s);
    s = fmaf(a1.x, b1.x, s); s = fmaf(a1.y, b1.y, s);
    s = fmaf(a1.z, b1.z, s); s = fmaf(a1.w, b1.w, s);
    s = fmaf(a2.x, b2.x, s); s = fmaf(a2.y, b2.y, s);
    s = fmaf(a2.z, b2.z, s); s = fmaf(a2.w, b2.w, s);
#pragma unroll
    for (int m = 1; m < 64; m <<= 1) s += __shfl_xor(s, m, 64);
    u64 p = pack_maxidx(s, ci);
    if (p > best) best = p;
  }
  if (lane == 0) wbest[wv] = best;
  __syncthreads();
  if (tid == 0) {
    u64 b0_ = wbest[0], b1_ = wbest[1], b2_ = wbest[2], b3_ = wbest[3];
    u64 m01 = b0_ > b1_ ? b0_ : b1_;
    u64 m23 = b2_ > b3_ ? b2_ : b3_;
    merged[row] = m01 > m23 ? m01 : m23;
  }
}

// ============================ FALLBACK (verified round-6) ===================

__global__ void noise_add_kernel(const float* __restrict__ in,
                                 float* __restrict__ noisy,
                                 u64* __restrict__ merged) {
  const unsigned i = blockIdx.x * blockDim.x + threadIdx.x;
  if (i >= EMB_N) return;
  if (i < M_TOT) merged[i] = 0ull;
  unsigned x0 = 0u, x1 = i;
  threefry2x32_042(x0, x1);
  noisy[i] = in[i] + bits_to_noise(x0 ^ x1);
}

__global__ __launch_bounds__(256) void gemm_argmax_kernel(
    const float* __restrict__ noisy, const float* __restrict__ table,
    u64* __restrict__ merged) {
  __shared__ float As[16][132];
  __shared__ float Bs[16][132];
  __shared__ float redm[128][16];
  __shared__ int   redi[128][16];

  const int tid = threadIdx.x;
  const int lane = tid & 63;
  const int w = tid >> 6;
  const int tx = lane & 7, ty = lane >> 3;
  const int col0 = (w & 1) * 64 + tx * 8;
  const int row0 = (w >> 1) * 64 + ty * 8;
  const int bm = blockIdx.x;
  const int split = blockIdx.y;
  const float* Abase = noisy + (size_t)bm * 128 * K_DIM;

  float rmax[8]; int ridx[8];
#pragma unroll
  for (int r = 0; r < 8; ++r) { rmax[r] = -INFINITY; ridx[r] = 0x7FFFFFFF; }

  for (int t = split; t < NTILES; t += NSPLIT) {
    const int nbase = t * 128;
    float acc[8][8];
#pragma unroll
    for (int r = 0; r < 8; ++r)
#pragma unroll
      for (int c = 0; c < 8; ++c) acc[r][c] = 0.0f;

    for (int k0 = 0; k0 < K_DIM; k0 += 16) {
      __syncthreads();
#pragma unroll
      for (int l = 0; l < 2; ++l) {
        const int e = tid + l * 256;
        const int ml = e >> 2, kk = (e & 3) << 2;
        float4 av = *(const float4*)(Abase + (size_t)ml * K_DIM + k0 + kk);
        As[kk + 0][ml] = av.x; As[kk + 1][ml] = av.y;
        As[kk + 2][ml] = av.z; As[kk + 3][ml] = av.w;
        const int n = nbase + ml;
        float4 bv = make_float4(0.f, 0.f, 0.f, 0.f);
        if (n < V_DIM)
          bv = *(const float4*)(table + (size_t)n * K_DIM + k0 + kk);
        Bs[kk + 0][ml] = bv.x; Bs[kk + 1][ml] = bv.y;
        Bs[kk + 2][ml] = bv.z; Bs[kk + 3][ml] = bv.w;
      }
      __syncthreads();
#pragma unroll
      for (int k = 0; k < 16; ++k) {
        float4 a0 = *(const float4*)&As[k][row0];
        float4 a1 = *(const float4*)&As[k][row0 + 4];
        float4 b0 = *(const float4*)&Bs[k][col0];
        float4 b1 = *(const float4*)&Bs[k][col0 + 4];
        float a[8] = {a0.x, a0.y, a0.z, a0.w, a1.x, a1.y, a1.z, a1.w};
        float b[8] = {b0.x, b0.y, b0.z, b0.w, b1.x, b1.y, b1.z, b1.w};
#pragma unroll
        for (int r = 0; r < 8; ++r)
#pragma unroll
          for (int c = 0; c < 8; ++c)
            acc[r][c] = fmaf(a[r], b[c], acc[r][c]);
      }
    }
#pragma unroll
    for (int r = 0; r < 8; ++r)
#pragma unroll
      for (int c = 0; c < 8; ++c) {
        const int n = nbase + col0 + c;
        if (n < V_DIM && acc[r][c] > rmax[r]) { rmax[r] = acc[r][c]; ridx[r] = n; }
      }
  }

  __syncthreads();
#pragma unroll
  for (int r = 0; r < 8; ++r) {
    redm[row0 + r][(w & 1) * 8 + tx] = rmax[r];
    redi[row0 + r][(w & 1) * 8 + tx] = ridx[r];
  }
  __syncthreads();
  if (tid < 128) {
    float best = -INFINITY; int bi = 0x7FFFFFFF;
#pragma unroll
    for (int j = 0; j < 16; ++j) {
      float v = redm[tid][j]; int id = redi[tid][j];
      if (v > best || (v == best && id < bi)) { best = v; bi = id; }
    }
    atomicMax(&merged[bm * 128 + tid], pack_maxidx(best, (unsigned)bi));
  }
}

// ---------------- shared: unpack index + gather table row -------------------
__global__ void gather_kernel(const u64* __restrict__ merged,
                              const float* __restrict__ table,
                              float* __restrict__ out) {
  const int row = blockIdx.x;
  const int tid = threadIdx.x;
  const unsigned bi = 0xFFFFFFFFu - (unsigned)(merged[row] & 0xFFFFFFFFull);
  if (tid < 192) {
    float4 val = *(const float4*)(table + (size_t)bi * K_DIM + tid * 4);
    *(float4*)(out + (size_t)row * K_DIM + tid * 4) = val;
  }
}

// ---------------- launch ----------------
extern "C" void kernel_launch(void* const* d_in, const int* in_sizes, int n_in,
                              void* d_out, int out_size, void* d_ws, size_t ws_size,
                              hipStream_t stream) {
  const float* inputs = (const float*)d_in[0];
  const float* table  = (const float*)d_in[1];
  if (n_in >= 2 && (in_sizes[0] == TAB_N || in_sizes[1] == EMB_N)) {
    table  = (const float*)d_in[0];
    inputs = (const float*)d_in[1];
  }
  float* out = (float*)d_out;
  float* noisy = out;   // overwritten by gather at the end

  // fast-path ws layout (bytes)
  const size_t oAh = 0;
  const size_t oBh = oAh + (size_t)EMB_N * 2;             //  6,291,456
  const size_t oCand = oBh + (size_t)PADV2 * K_DIM * 2;   // 83,755,008
  const size_t oMerged = oCand + (size_t)M_TOT * NCAND * 4;
  const size_t REQ = oMerged + (size_t)M_TOT * 8;         // ~84.9 MB

  if (ws_size >= REQ) {
    unsigned short* Ah = (unsigned short*)((char*)d_ws + oAh);
    unsigned short* Bh = (unsigned short*)((char*)d_ws + oBh);
    unsigned* cand = (unsigned*)((char*)d_ws + oCand);
    u64* merged = (u64*)((char*)d_ws + oMerged);

    prep_kernel<<<NOISE_BLK + BSPLIT_BLK, 256, 0, stream>>>(inputs, table, noisy, Ah, Bh);
    dim3 g2(M_TOT / 256, GSPLIT);   // 16 x 32 = 512 blocks
    mfma_cand_kernel<<<g2, 512, 0, stream>>>(Ah, Bh, cand);
    rescore_kernel<<<M_TOT, 256, 0, stream>>>(noisy, table, cand, merged);
    gather_kernel<<<M_TOT, 256, 0, stream>>>(merged, table, out);
  } else {
    u64* merged = (u64*)d_ws;
    noise_add_kernel<<<EMB_N / 256, 256, 0, stream>>>(inputs, noisy, merged);
    dim3 g2(M_TOT / 128, NSPLIT);
    gemm_argmax_kernel<<<g2, 256, 0, stream>>>(noisy, table, merged);
    gather_kernel<<<M_TOT, 256, 0, stream>>>(merged, table, out);
  }
}

// Round 18
// 431.274 us; speedup vs baseline: 2.4697x; 1.1256x over previous
//
#include <hip/hip_runtime.h>
#include <hip/hip_bf16.h>
#include <float.h>
#include <math.h>

#define K_DIM 768
#define V_DIM 50257
#define M_TOT 4096
#define EMB_N 3145728            // 2*2048*768
#define TAB_N 38597376           // 50257*768
#define NT256 197                // N tiles of 256
#define PADV2 50432              // 197*256 padded vocab
#define GSPLIT 16                // N splits (1 block/CU, single pass)
#define NCAND 32                 // GSPLIT * top2
#define NSPLIT 16                // fallback fp32 kernel splits
#define NTILES ((V_DIM + 127) / 128)
#define NOISE_BLK (EMB_N / 256)                  // 12288
#define BSPLIT_BLK ((PADV2 * K_DIM / 4) / 256)   // 37824

typedef __attribute__((ext_vector_type(8))) short short8;
typedef __attribute__((ext_vector_type(4))) float f32x4;
typedef unsigned long long u64;

// ---------------- JAX threefry2x32 (key = (0, 42)), 20 rounds ----------------
__device__ __forceinline__ unsigned rotl32(unsigned v, int d) {
  return (v << d) | (v >> (32 - d));
}
__device__ __forceinline__ void threefry2x32_042(unsigned& x0, unsigned& x1) {
  const unsigned ks0 = 0u, ks1 = 42u;
  const unsigned ks2 = ks0 ^ ks1 ^ 0x1BD11BDAu;
  x0 += ks0; x1 += ks1;
#define TF_R(r) { x0 += x1; x1 = rotl32(x1, (r)); x1 ^= x0; }
  TF_R(13) TF_R(15) TF_R(26) TF_R(6)
  x0 += ks1; x1 += ks2 + 1u;
  TF_R(17) TF_R(29) TF_R(16) TF_R(24)
  x0 += ks2; x1 += ks0 + 2u;
  TF_R(13) TF_R(15) TF_R(26) TF_R(6)
  x0 += ks0; x1 += ks1 + 3u;
  TF_R(17) TF_R(29) TF_R(16) TF_R(24)
  x0 += ks1; x1 += ks2 + 4u;
  TF_R(13) TF_R(15) TF_R(26) TF_R(6)
  x0 += ks2; x1 += ks0 + 5u;
#undef TF_R
}

// bits -> uniform(-1+2^-24, 1) -> laplace -> /5  (exact JAX op sequence)
__device__ __forceinline__ float bits_to_noise(unsigned bits) {
  unsigned fb = (bits >> 9) | 0x3F800000u;
  float f = __uint_as_float(fb) - 1.0f;
  const float minv = -0.99999994039535522461f;
  float u = __fadd_rn(__fmul_rn(f, 2.0f), minv);
  u = fmaxf(minv, u);
  float s = (u > 0.0f) ? 1.0f : ((u < 0.0f) ? -1.0f : 0.0f);
  float l = s * log1pf(-fabsf(u));
  return __fdiv_rn(l, 5.0f);
}

__device__ __forceinline__ float bf2f(unsigned short b) {
  return __uint_as_float(((unsigned)b) << 16);
}
__device__ __forceinline__ unsigned short f2bf(float x) {
  __hip_bfloat16 h = __float2bfloat16(x);   // RNE
  return *(unsigned short*)&h;
}

// monotone u32 key of float (order-preserving)
__device__ __forceinline__ unsigned fkey(float v) {
  unsigned b = __float_as_uint(v);
  return b ^ (((unsigned)((int)b >> 31)) | 0x80000000u);
}
__device__ __forceinline__ u64 pack_maxidx(float v, unsigned idx) {
  return ((u64)fkey(v) << 32) | (u64)(0xFFFFFFFFu - idx);
}
__device__ __forceinline__ unsigned umax32(unsigned a, unsigned b) { return a > b ? a : b; }
__device__ __forceinline__ unsigned umin32(unsigned a, unsigned b) { return a < b ? a : b; }

__device__ __forceinline__ void gload16(const void* g, void* l) {
  __builtin_amdgcn_global_load_lds(
      (const __attribute__((address_space(1))) unsigned*)g,
      (__attribute__((address_space(3))) unsigned*)l, 16, 0, 0);
}

// ============================ FAST PATH ====================================

// fused prep: noisy(f32)->d_out + Ah bf16; table -> Bh bf16 (pad to PADV2)
__global__ void prep_kernel(const float* __restrict__ in,
                            const float* __restrict__ tab,
                            float* __restrict__ noisy,
                            unsigned short* __restrict__ Ah,
                            unsigned short* __restrict__ Bh) {
  if (blockIdx.x < NOISE_BLK) {
    const unsigned i = blockIdx.x * 256 + threadIdx.x;
    unsigned x0 = 0u, x1 = i;
    threefry2x32_042(x0, x1);
    float v = in[i] + bits_to_noise(x0 ^ x1);
    noisy[i] = v;
    Ah[i] = f2bf(v);
  } else {
    const size_t i = ((size_t)(blockIdx.x - NOISE_BLK) * 256 + threadIdx.x) * 4;
    ushort4 h;
    if (i < (size_t)TAB_N) {
      float4 v = *(const float4*)(tab + i);
      h.x = f2bf(v.x); h.y = f2bf(v.y); h.z = f2bf(v.z); h.w = f2bf(v.w);
    } else {
      h = make_ushort4(0, 0, 0, 0);
    }
    *(ushort4*)(Bh + i) = h;
  }
}

// 256x256-tile, 8-wave bf16 MFMA GEMM, counted-vmcnt double-buffer (r16/r17)
// + deferred-register fold (r17) + T5 setprio around MFMA clusters (waves
// drift between the per-kt barriers -> role-split exists -> setprio can
// favor MFMA-issuing waves) + GSPLIT=16 (256 blocks = 1/CU, single pass;
// 12-bit low field: local = tidx*256+col <= 3327, key[31:12]).
__global__ __launch_bounds__(512, 2) void mfma_cand_kernel(
    const unsigned short* __restrict__ Ah,
    const unsigned short* __restrict__ Bh,
    unsigned* __restrict__ cand) {
  __shared__ alignas(16) char lds[131072];
  __shared__ unsigned topscr[256][4][2];

  const int tid = threadIdx.x;
  const int lane = tid & 63, w = tid >> 6;
  const int fr = lane & 15, g = lane >> 4;
  const int WM = w >> 2, WN = w & 3;       // 2 x 4 wave grid
  const int wr = WM * 128, wc = WN * 64;   // wave tile: 128 rows x 64 cols
  const int bm = blockIdx.x, split = blockIdx.y;

  // staging descriptors: 4 iters x 512 thr x 16B = 32KB per operand/K-tile
  int srowv[4], scolv[4], soffv[4];
#pragma unroll
  for (int i = 0; i < 4; ++i) {
    int s = i * 512 + tid;                 // 16B-slot 0..2047
    int row = s >> 3, p = s & 7;           // 8 slots (128B) per row
    srowv[i] = row;
    scolv[i] = (p ^ (row & 7)) * 8;        // pre-swizzled source elem offset
    soffv[i] = i * 8192 + w * 1024;        // wave-uniform LDS byte base
  }

  const size_t abase = (size_t)bm * 256 * K_DIM;

#define STAGE(buf, bb, kofs) do {                                              \
    _Pragma("unroll")                                                          \
    for (int i_ = 0; i_ < 4; ++i_) {                                           \
      gload16(Ah + abase + (size_t)srowv[i_] * K_DIM + (kofs) + scolv[i_],     \
              lds + (buf) * 65536 + soffv[i_]);                                \
      gload16(Bh + (bb) + (size_t)srowv[i_] * K_DIM + (kofs) + scolv[i_],      \
              lds + (buf) * 65536 + 32768 + soffv[i_]);                        \
    } } while (0)

  // deferred per-thread running top-2 per (m,j), u32 packed keys
  unsigned r1[8][4], r2[8][4];
#pragma unroll
  for (int m = 0; m < 8; ++m)
#pragma unroll
    for (int j = 0; j < 4; ++j) { r1[m][j] = 0u; r2[m][j] = 0u; }

  // prologue: stage K-tiles 0 and 1 of the first tile (16 loads in flight)
  {
    const size_t bb0 = (size_t)split * 256 * K_DIM;
    STAGE(0, bb0, 0);
    STAGE(1, bb0, 64);
  }

  int tidx = 0;   // tile counter within split (0..12)
  for (int t = split; t < NT256; t += GSPLIT, ++tidx) {
    f32x4 acc[8][4];
#pragma unroll
    for (int m = 0; m < 8; ++m)
#pragma unroll
      for (int n = 0; n < 4; ++n) acc[m][n] = (f32x4){0.f, 0.f, 0.f, 0.f};

    const size_t bbase = (size_t)t * 256 * K_DIM;
    const int tnext = (t + GSPLIT < NT256) ? (t + GSPLIT) : t;  // clamp: last
    const size_t bnext = (size_t)tnext * 256 * K_DIM;           // stages dummy

    for (int kt = 0; kt < K_DIM / 64; ++kt) {
      // wait ONLY the 8 loads of this K-tile (issued 2 K-tiles ago);
      // the 8 newer loads stay in flight across the barrier (T4).
      asm volatile("s_waitcnt vmcnt(8)" ::: "memory");
      __builtin_amdgcn_s_barrier();
      __builtin_amdgcn_sched_barrier(0);

      const char* lA = lds + (kt & 1) * 65536;
      const char* lB = lA + 32768;
#pragma unroll
      for (int kh = 0; kh < 2; ++kh) {
        short8 bfv[4];
#pragma unroll
        for (int n = 0; n < 4; ++n) {
          const int row = wc + n * 16 + fr;
          const int p = (kh * 4 + g) ^ (row & 7);
          bfv[n] = *(const short8*)(lB + row * 128 + p * 16);
        }
#pragma unroll
        for (int mh = 0; mh < 2; ++mh) {
          short8 afv[4];
#pragma unroll
          for (int mi = 0; mi < 4; ++mi) {
            const int row = wr + (mh * 4 + mi) * 16 + fr;
            const int p = (kh * 4 + g) ^ (row & 7);
            afv[mi] = *(const short8*)(lA + row * 128 + p * 16);
          }
          __builtin_amdgcn_s_setprio(1);   // T5: favor MFMA-issuing wave
#pragma unroll
          for (int mi = 0; mi < 4; ++mi)
#pragma unroll
            for (int n = 0; n < 4; ++n)
              acc[mh * 4 + mi][n] = __builtin_amdgcn_mfma_f32_16x16x32_bf16(
                  afv[mi], bfv[n], acc[mh * 4 + mi][n], 0, 0, 0);
          __builtin_amdgcn_s_setprio(0);
        }
      }

      asm volatile("s_waitcnt lgkmcnt(0)" ::: "memory");
      __builtin_amdgcn_s_barrier();        // all waves done reading this buf
      __builtin_amdgcn_sched_barrier(0);

      // refill the just-read buffer with K-tile kt+2 (next tile if kt>=10)
      const int kn = kt + 2;
      if (kn < K_DIM / 64) {
        STAGE(kt & 1, bbase, kn * 64);
      } else {
        STAGE(kt & 1, bnext, (kn - K_DIM / 64) * 64);
      }
    }

    // ---- per-tile fold into running registers (no barriers, no shfl) ----
    unsigned lowf[4];
#pragma unroll
    for (int n = 0; n < 4; ++n)
      lowf[n] = 4095u - (unsigned)(tidx * 256 + wc + n * 16 + fr);

#pragma unroll
    for (int m = 0; m < 8; ++m)
#pragma unroll
      for (int j = 0; j < 4; ++j) {
        unsigned p0 = (fkey(acc[m][0][j]) & 0xFFFFF000u) | lowf[0];
        unsigned p1 = (fkey(acc[m][1][j]) & 0xFFFFF000u) | lowf[1];
        unsigned p2 = (fkey(acc[m][2][j]) & 0xFFFFF000u) | lowf[2];
        unsigned p3 = (fkey(acc[m][3][j]) & 0xFFFFF000u) | lowf[3];
        unsigned a1 = umax32(p0, p1), a2 = umin32(p0, p1);
        unsigned b1 = umax32(p2, p3), b2 = umin32(p2, p3);
        unsigned t1 = umax32(a1, b1);
        unsigned t2 = umax32(umin32(a1, b1), umax32(a2, b2));
        if (t1 > r1[m][j]) { r2[m][j] = umax32(r1[m][j], t2); r1[m][j] = t1; }
        else r2[m][j] = umax32(r2[m][j], t1);
      }
  }
#undef STAGE

  // ---- ONE cross-lane butterfly + topscr merge at the end ----
#pragma unroll
  for (int m = 0; m < 8; ++m)
#pragma unroll
    for (int j = 0; j < 4; ++j) {
      unsigned t1 = r1[m][j], t2 = r2[m][j];
#pragma unroll
      for (int msk = 1; msk < 16; msk <<= 1) {
        unsigned o1 = (unsigned)__shfl_xor((int)t1, msk, 64);
        unsigned o2 = (unsigned)__shfl_xor((int)t2, msk, 64);
        if (o1 > t1) { t2 = umax32(t1, o2); t1 = o1; }
        else t2 = umax32(t2, o1);
      }
      if (fr == 0) {
        int rl = wr + m * 16 + g * 4 + j;   // 0..255
        topscr[rl][WN][0] = t1;
        topscr[rl][WN][1] = t2;
      }
    }
  __syncthreads();

  if (tid < 256) {
    unsigned m1 = topscr[tid][0][0], m2 = topscr[tid][0][1];
#pragma unroll
    for (int q = 1; q < 4; ++q) {
      unsigned c1 = topscr[tid][q][0], c2 = topscr[tid][q][1];
      if (c1 > m1) { m2 = umax32(m1, c2); m1 = c1; }
      else m2 = umax32(m2, c1);
    }
    unsigned l1 = 4095u - (m1 & 0xFFFu);
    unsigned l2 = 4095u - (m2 & 0xFFFu);
    unsigned c1 = (unsigned)((split + (l1 >> 8) * GSPLIT) * 256) + (l1 & 255u);
    unsigned c2 = (unsigned)((split + (l2 >> 8) * GSPLIT) * 256) + (l2 & 255u);
    if (c1 >= V_DIM) c1 = 0;
    if (c2 >= V_DIM) c2 = 0;
    int grow = bm * 256 + tid;
    cand[(grow * GSPLIT + split) * 2 + 0] = c1;
    cand[(grow * GSPLIT + split) * 2 + 1] = c2;
  }
}

// fp32 rescore of NCAND candidates/row, coalesced (verified rounds 11-17)
__global__ __launch_bounds__(256) void rescore_kernel(
    const float* __restrict__ noisy, const float* __restrict__ table,
    const unsigned* __restrict__ cand, u64* __restrict__ merged) {
  __shared__ u64 wbest[4];
  const int row = blockIdx.x;
  const int tid = threadIdx.x, lane = tid & 63, wv = tid >> 6;
  const float* a = noisy + (size_t)row * K_DIM + lane * 12;
  float4 a0 = *(const float4*)(a);
  float4 a1 = *(const float4*)(a + 4);
  float4 a2 = *(const float4*)(a + 8);

  u64 best = 0;
  for (int c = wv; c < NCAND; c += 4) {
    const unsigned ci = cand[row * NCAND + c];
    const float* b = table + (size_t)ci * K_DIM + lane * 12;
    float4 b0 = *(const float4*)(b);
    float4 b1 = *(const float4*)(b + 4);
    float4 b2 = *(const float4*)(b + 8);
    float s = 0.f;
    s = fmaf(a0.x, b0.x, s); s = fmaf(a0.y, b0.y, s);
    s = fmaf(a0.z, b0.z, s); s = fmaf(a0.w, b0.w, s);
    s = fmaf(a1.x, b1.x, s); s = fmaf(a1.y, b1.y, s);
    s = fmaf(a1.z, b1.z, s); s = fmaf(a1.w, b1.w, s);
    s = fmaf(a2.x, b2.x, s); s = fmaf(a2.y, b2.y, s);
    s = fmaf(a2.z, b2.z, s); s = fmaf(a2.w, b2.w, s);
#pragma unroll
    for (int m = 1; m < 64; m <<= 1) s += __shfl_xor(s, m, 64);
    u64 p = pack_maxidx(s, ci);
    if (p > best) best = p;
  }
  if (lane == 0) wbest[wv] = best;
  __syncthreads();
  if (tid == 0) {
    u64 b0_ = wbest[0], b1_ = wbest[1], b2_ = wbest[2], b3_ = wbest[3];
    u64 m01 = b0_ > b1_ ? b0_ : b1_;
    u64 m23 = b2_ > b3_ ? b2_ : b3_;
    merged[row] = m01 > m23 ? m01 : m23;
  }
}

// ============================ FALLBACK (verified round-6) ===================

__global__ void noise_add_kernel(const float* __restrict__ in,
                                 float* __restrict__ noisy,
                                 u64* __restrict__ merged) {
  const unsigned i = blockIdx.x * blockDim.x + threadIdx.x;
  if (i >= EMB_N) return;
  if (i < M_TOT) merged[i] = 0ull;
  unsigned x0 = 0u, x1 = i;
  threefry2x32_042(x0, x1);
  noisy[i] = in[i] + bits_to_noise(x0 ^ x1);
}

__global__ __launch_bounds__(256) void gemm_argmax_kernel(
    const float* __restrict__ noisy, const float* __restrict__ table,
    u64* __restrict__ merged) {
  __shared__ float As[16][132];
  __shared__ float Bs[16][132];
  __shared__ float redm[128][16];
  __shared__ int   redi[128][16];

  const int tid = threadIdx.x;
  const int lane = tid & 63;
  const int w = tid >> 6;
  const int tx = lane & 7, ty = lane >> 3;
  const int col0 = (w & 1) * 64 + tx * 8;
  const int row0 = (w >> 1) * 64 + ty * 8;
  const int bm = blockIdx.x;
  const int split = blockIdx.y;
  const float* Abase = noisy + (size_t)bm * 128 * K_DIM;

  float rmax[8]; int ridx[8];
#pragma unroll
  for (int r = 0; r < 8; ++r) { rmax[r] = -INFINITY; ridx[r] = 0x7FFFFFFF; }

  for (int t = split; t < NTILES; t += NSPLIT) {
    const int nbase = t * 128;
    float acc[8][8];
#pragma unroll
    for (int r = 0; r < 8; ++r)
#pragma unroll
      for (int c = 0; c < 8; ++c) acc[r][c] = 0.0f;

    for (int k0 = 0; k0 < K_DIM; k0 += 16) {
      __syncthreads();
#pragma unroll
      for (int l = 0; l < 2; ++l) {
        const int e = tid + l * 256;
        const int ml = e >> 2, kk = (e & 3) << 2;
        float4 av = *(const float4*)(Abase + (size_t)ml * K_DIM + k0 + kk);
        As[kk + 0][ml] = av.x; As[kk + 1][ml] = av.y;
        As[kk + 2][ml] = av.z; As[kk + 3][ml] = av.w;
        const int n = nbase + ml;
        float4 bv = make_float4(0.f, 0.f, 0.f, 0.f);
        if (n < V_DIM)
          bv = *(const float4*)(table + (size_t)n * K_DIM + k0 + kk);
        Bs[kk + 0][ml] = bv.x; Bs[kk + 1][ml] = bv.y;
        Bs[kk + 2][ml] = bv.z; Bs[kk + 3][ml] = bv.w;
      }
      __syncthreads();
#pragma unroll
      for (int k = 0; k < 16; ++k) {
        float4 a0 = *(const float4*)&As[k][row0];
        float4 a1 = *(const float4*)&As[k][row0 + 4];
        float4 b0 = *(const float4*)&Bs[k][col0];
        float4 b1 = *(const float4*)&Bs[k][col0 + 4];
        float a[8] = {a0.x, a0.y, a0.z, a0.w, a1.x, a1.y, a1.z, a1.w};
        float b[8] = {b0.x, b0.y, b0.z, b0.w, b1.x, b1.y, b1.z, b1.w};
#pragma unroll
        for (int r = 0; r < 8; ++r)
#pragma unroll
          for (int c = 0; c < 8; ++c)
            acc[r][c] = fmaf(a[r], b[c], acc[r][c]);
      }
    }
#pragma unroll
    for (int r = 0; r < 8; ++r)
#pragma unroll
      for (int c = 0; c < 8; ++c) {
        const int n = nbase + col0 + c;
        if (n < V_DIM && acc[r][c] > rmax[r]) { rmax[r] = acc[r][c]; ridx[r] = n; }
      }
  }

  __syncthreads();
#pragma unroll
  for (int r = 0; r < 8; ++r) {
    redm[row0 + r][(w & 1) * 8 + tx] = rmax[r];
    redi[row0 + r][(w & 1) * 8 + tx] = ridx[r];
  }
  __syncthreads();
  if (tid < 128) {
    float best = -INFINITY; int bi = 0x7FFFFFFF;
#pragma unroll
    for (int j = 0; j < 16; ++j) {
      float v = redm[tid][j]; int id = redi[tid][j];
      if (v > best || (v == best && id < bi)) { best = v; bi = id; }
    }
    atomicMax(&merged[bm * 128 + tid], pack_maxidx(best, (unsigned)bi));
  }
}

// ---------------- shared: unpack index + gather table row -------------------
__global__ void gather_kernel(const u64* __restrict__ merged,
                              const float* __restrict__ table,
                              float* __restrict__ out) {
  const int row = blockIdx.x;
  const int tid = threadIdx.x;
  const unsigned bi = 0xFFFFFFFFu - (unsigned)(merged[row] & 0xFFFFFFFFull);
  if (tid < 192) {
    float4 val = *(const float4*)(table + (size_t)bi * K_DIM + tid * 4);
    *(float4*)(out + (size_t)row * K_DIM + tid * 4) = val;
  }
}

// ---------------- launch ----------------
extern "C" void kernel_launch(void* const* d_in, const int* in_sizes, int n_in,
                              void* d_out, int out_size, void* d_ws, size_t ws_size,
                              hipStream_t stream) {
  const float* inputs = (const float*)d_in[0];
  const float* table  = (const float*)d_in[1];
  if (n_in >= 2 && (in_sizes[0] == TAB_N || in_sizes[1] == EMB_N)) {
    table  = (const float*)d_in[0];
    inputs = (const float*)d_in[1];
  }
  float* out = (float*)d_out;
  float* noisy = out;   // overwritten by gather at the end

  // fast-path ws layout (bytes)
  const size_t oAh = 0;
  const size_t oBh = oAh + (size_t)EMB_N * 2;             //  6,291,456
  const size_t oCand = oBh + (size_t)PADV2 * K_DIM * 2;   // 83,755,008
  const size_t oMerged = oCand + (size_t)M_TOT * NCAND * 4;
  const size_t REQ = oMerged + (size_t)M_TOT * 8;         // ~84.8 MB

  if (ws_size >= REQ) {
    unsigned short* Ah = (unsigned short*)((char*)d_ws + oAh);
    unsigned short* Bh = (unsigned short*)((char*)d_ws + oBh);
    unsigned* cand = (unsigned*)((char*)d_ws + oCand);
    u64* merged = (u64*)((char*)d_ws + oMerged);

    prep_kernel<<<NOISE_BLK + BSPLIT_BLK, 256, 0, stream>>>(inputs, table, noisy, Ah, Bh);
    dim3 g2(M_TOT / 256, GSPLIT);   // 16 x 16 = 256 blocks, exactly 1/CU
    mfma_cand_kernel<<<g2, 512, 0, stream>>>(Ah, Bh, cand);
    rescore_kernel<<<M_TOT, 256, 0, stream>>>(noisy, table, cand, merged);
    gather_kernel<<<M_TOT, 256, 0, stream>>>(merged, table, out);
  } else {
    u64* merged = (u64*)d_ws;
    noise_add_kernel<<<EMB_N / 256, 256, 0, stream>>>(inputs, noisy, merged);
    dim3 g2(M_TOT / 128, NSPLIT);
    gemm_argmax_kernel<<<g2, 256, 0, stream>>>(noisy, table, merged);
    gather_kernel<<<M_TOT, 256, 0, stream>>>(merged, table, out);
  }
}